// Round 9
// baseline (482.176 us; speedup 1.0000x reference)
//
#include <hip/hip_runtime.h>
#include <hip/hip_fp16.h>
#include <math.h>

#define NN   50000
#define EE   800000
#define IND  128
#define EDD  16
#define HIDD 32
#define NH   4
#define HC   128     // NH*HIDD
#define OUTD 64
#define NEG  0.1f
#define BN_EPS 1e-5f
#define LOG2E 1.44269504088896340736f

typedef __attribute__((ext_vector_type(2))) float v2f;
typedef __attribute__((ext_vector_type(2))) _Float16 v2h;

#if defined(__has_builtin)
#  if __has_builtin(__builtin_amdgcn_fdot2)
#    define HAVE_FDOT2 1
#  else
#    define HAVE_FDOT2 0
#  endif
#else
#  define HAVE_FDOT2 0
#endif

__device__ __forceinline__ float lrelu(float x) { return fmaxf(x, NEG * x); }
__device__ __forceinline__ v2f lrelu2(v2f v) { return __builtin_elementwise_max(v, v * NEG); }
__device__ __forceinline__ float2 unpk(float f) {
    return __half22float2(__builtin_bit_cast(__half2, f));
}

// DPP rotate-add: sum over the 16-lane head group without LDS-pipe traffic.
#define DPPADD(p, CTRL) do {                                                     \
    int _t = __builtin_amdgcn_update_dpp(0, __builtin_bit_cast(int, (p)),        \
                                         (CTRL), 0xF, 0xF, true);                \
    (p) += __builtin_bit_cast(float, _t);                                        \
} while (0)

// ---------------- weight fold/transpose (tiny, runs before count+embed) ----------
__global__ void fold_kernel(const float* __restrict__ W0, const float* __restrict__ b0,
                            const float* __restrict__ g, const float* __restrict__ bb,
                            const float* __restrict__ bm, const float* __restrict__ bv,
                            const float* __restrict__ Wl0, const float* __restrict__ Wr0,
                            const float* __restrict__ Wl1, const float* __restrict__ Wr1,
                            const float* __restrict__ We0, const float* __restrict__ We1,
                            float* __restrict__ w0t, float* __restrict__ b0f,
                            float* __restrict__ wlt0, float* __restrict__ wrt0,
                            float* __restrict__ wlt1, float* __restrict__ wrt1,
                            __half2* __restrict__ weh0, __half2* __restrict__ weh1) {
    int tid = threadIdx.x;
    for (int idx = tid; idx < IND * HIDD; idx += 256) {
        int k = idx >> 5, c = idx & 31;
        float s = g[c] * (1.0f / sqrtf(bv[c] + BN_EPS));
        w0t[idx] = W0[c * IND + k] * s;
    }
    if (tid < HIDD) {
        float s = g[tid] * (1.0f / sqrtf(bv[tid] + BN_EPS));
        b0f[tid] = (b0[tid] - bm[tid]) * s + bb[tid];
    }
    for (int idx = tid; idx < HIDD * HC; idx += 256) {
        int k = idx >> 7, c = idx & 127;
        wlt0[idx] = Wl0[c * HIDD + k];
        wrt0[idx] = Wr0[c * HIDD + k];
        wlt1[idx] = Wl1[c * HIDD + k];
        wrt1[idx] = Wr1[c * HIDD + k];
    }
    // We -> half2 pairs: weh[c*8 + k] = (We[c][2k], We[c][2k+1])
    for (int idx = tid; idx < HC * 8; idx += 256) {
        int c = idx >> 3, k = idx & 7;
        weh0[idx] = __floats2half2_rn(We0[c * EDD + 2 * k], We0[c * EDD + 2 * k + 1]);
        weh1[idx] = __floats2half2_rn(We1[c * EDD + 2 * k], We1[c * EDD + 2 * k + 1]);
    }
}

// ---------------- merged: degree count (fire-and-forget) + embed (VALU) -----------
// Blocks [0, EE/256): count via NON-RETURNING atomics -> waves retire immediately.
// Blocks [EE/256, EE/256+NN/8): embed+layer-0 linear.
__global__ void count_embed_kernel(const int* __restrict__ ei, int* __restrict__ cnt,
                                   const float* __restrict__ x,
                                   const float* __restrict__ w0t, const float* __restrict__ b0f,
                                   const float* __restrict__ wlt, const float* __restrict__ bl,
                                   const float* __restrict__ wrt, const float* __restrict__ br,
                                   __half2* __restrict__ xl, float* __restrict__ xr) {
    if (blockIdx.x < EE / 256) {
        int e = blockIdx.x * 256 + threadIdx.x;
        atomicAdd(&cnt[ei[EE + e]], 1);   // result unused -> no-return atomic, no stall
        return;
    }
    int tid = threadIdx.x;
    int n0 = (blockIdx.x - EE / 256) * 8;
    __shared__ float sx[8 * IND];
    __shared__ float se[8][HIDD];
    *(float4*)(sx + tid * 4) = *(const float4*)(x + (size_t)n0 * IND + tid * 4);
    __syncthreads();
    {
        int r = tid >> 5, c = tid & 31;
        float acc = b0f[c];
        const float* xrow = sx + r * IND;
        #pragma unroll 8
        for (int k = 0; k < IND; k++) acc += xrow[k] * w0t[k * HIDD + c];
        se[r][c] = lrelu(acc);
    }
    __syncthreads();
    int mat = tid >> 7, grp = (tid >> 6) & 1, pr = tid & 63;
    int c0 = 2 * pr;
    const float* WT = mat ? wrt : wlt;
    const float* b  = mat ? br : bl;
    v2f bv2 = (v2f){b[c0], b[c0 + 1]};
    v2f a0 = bv2, a1 = bv2, a2 = bv2, a3 = bv2;
    int nb = grp * 4;
    #pragma unroll
    for (int k = 0; k < HIDD; k++) {
        v2f wk = *(const v2f*)(WT + k * HC + c0);
        a0 += wk * se[nb + 0][k]; a1 += wk * se[nb + 1][k];
        a2 += wk * se[nb + 2][k]; a3 += wk * se[nb + 3][k];
    }
    if (mat == 0) {
        xl[((unsigned)(n0 + nb + 0) << 6) + pr] = __floats2half2_rn(a0.x, a0.y);
        xl[((unsigned)(n0 + nb + 1) << 6) + pr] = __floats2half2_rn(a1.x, a1.y);
        xl[((unsigned)(n0 + nb + 2) << 6) + pr] = __floats2half2_rn(a2.x, a2.y);
        xl[((unsigned)(n0 + nb + 3) << 6) + pr] = __floats2half2_rn(a3.x, a3.y);
    } else {
        *(float2*)(xr + ((unsigned)(n0 + nb + 0) << 7) + c0) = make_float2(a0.x, a0.y);
        *(float2*)(xr + ((unsigned)(n0 + nb + 1) << 7) + c0) = make_float2(a1.x, a1.y);
        *(float2*)(xr + ((unsigned)(n0 + nb + 2) << 7) + c0) = make_float2(a2.x, a2.y);
        *(float2*)(xr + ((unsigned)(n0 + nb + 3) << 7) + c0) = make_float2(a3.x, a3.y);
    }
}

// parallel exclusive scan of cnt[NN] -> rowstart[NN+1]
__global__ void scan1_kernel(const int* cnt, int* pre, int* bsum) {
    int i = blockIdx.x * 1024 + threadIdx.x;
    int lane = threadIdx.x & 63, wid = threadIdx.x >> 6;
    __shared__ int wsum[16];
    int v = (i < NN) ? cnt[i] : 0;
    int s = v;
    #pragma unroll
    for (int off = 1; off < 64; off <<= 1) {
        int t = __shfl_up(s, off);
        if (lane >= off) s += t;
    }
    if (lane == 63) wsum[wid] = s;
    __syncthreads();
    if (wid == 0) {
        int ws = (lane < 16) ? wsum[lane] : 0;
        #pragma unroll
        for (int off = 1; off < 16; off <<= 1) {
            int t = __shfl_up(ws, off);
            if (lane >= off) ws += t;
        }
        if (lane < 16) wsum[lane] = ws;
    }
    __syncthreads();
    int woff = (wid > 0) ? wsum[wid - 1] : 0;
    if (i < NN) pre[i] = woff + s - v;
    if (threadIdx.x == 1023) bsum[blockIdx.x] = wsum[15];
}

// also emits cursor[] = rowstart copy for scatter's fetch-add
__global__ void scan3_kernel(int* rowstart, int* cursor, const int* pre,
                             const int* bsum, int nb) {
    __shared__ int boff_s;
    if (threadIdx.x < 64) {
        int lane = threadIdx.x;
        int v = (lane < nb) ? bsum[lane] : 0;
        int s = v;
        #pragma unroll
        for (int off = 1; off < 64; off <<= 1) {
            int t = __shfl_up(s, off);
            if (lane >= off) s += t;
        }
        if (lane == (int)blockIdx.x) boff_s = s - v;
    }
    __syncthreads();
    int i = blockIdx.x * 1024 + threadIdx.x;
    if (i < NN) {
        int r = pre[i] + boff_s;
        rowstart[i] = r;
        cursor[i] = r;
    }
    if (i == 0) rowstart[NN] = EE;
}

// scatter with in-kernel rank acquisition: pos = fetch_add(cursor[d]).
// The returning atomic overlaps with this kernel's own eattr reads + random writes.
__global__ void scatter_kernel(const int* __restrict__ ei, int* __restrict__ cursor,
                               const float* __restrict__ eattr,
                               int* __restrict__ csr_src, __half2* __restrict__ ea16) {
    int e = blockIdx.x * blockDim.x + threadIdx.x;
    if (e >= EE) return;
    int s = ei[e];
    int d = ei[EE + e];
    // issue eattr loads before the atomic so both are in flight together
    const float4* src = (const float4*)(eattr + ((size_t)e << 4));
    float4 q0 = src[0], q1 = src[1], q2 = src[2], q3 = src[3];
    int pos = atomicAdd(&cursor[d], 1);
    __half2 h[8];
    h[0] = __floats2half2_rn(q0.x, q0.y); h[1] = __floats2half2_rn(q0.z, q0.w);
    h[2] = __floats2half2_rn(q1.x, q1.y); h[3] = __floats2half2_rn(q1.z, q1.w);
    h[4] = __floats2half2_rn(q2.x, q2.y); h[5] = __floats2half2_rn(q2.z, q2.w);
    h[6] = __floats2half2_rn(q3.x, q3.y); h[7] = __floats2half2_rn(q3.z, q3.w);
    csr_src[pos] = s;
    float4* dst = (float4*)(ea16 + ((size_t)pos << 3));
    dst[0] = *(float4*)&h[0];
    dst[1] = *(float4*)&h[4];
}

// ---------------- per-layer linear: h1 -> xl (fp16), xr (fp32); 8 nodes/block ------
__global__ void lin_kernel(const float* __restrict__ f,
                           const float* __restrict__ wlt, const float* __restrict__ bl,
                           const float* __restrict__ wrt, const float* __restrict__ br,
                           __half2* __restrict__ xl, float* __restrict__ xr) {
    int tid = threadIdx.x;
    int n0 = blockIdx.x * 8;
    __shared__ float se[8][HIDD];
    se[tid >> 5][tid & 31] = f[((unsigned)(n0 + (tid >> 5)) << 5) + (tid & 31)];
    __syncthreads();
    int mat = tid >> 7, grp = (tid >> 6) & 1, pr = tid & 63;
    int c0 = 2 * pr;
    const float* WT = mat ? wrt : wlt;
    const float* b  = mat ? br : bl;
    v2f bv2 = (v2f){b[c0], b[c0 + 1]};
    v2f a0 = bv2, a1 = bv2, a2 = bv2, a3 = bv2;
    int nb = grp * 4;
    #pragma unroll
    for (int k = 0; k < HIDD; k++) {
        v2f wk = *(const v2f*)(WT + k * HC + c0);
        a0 += wk * se[nb + 0][k]; a1 += wk * se[nb + 1][k];
        a2 += wk * se[nb + 2][k]; a3 += wk * se[nb + 3][k];
    }
    if (mat == 0) {
        xl[((unsigned)(n0 + nb + 0) << 6) + pr] = __floats2half2_rn(a0.x, a0.y);
        xl[((unsigned)(n0 + nb + 1) << 6) + pr] = __floats2half2_rn(a1.x, a1.y);
        xl[((unsigned)(n0 + nb + 2) << 6) + pr] = __floats2half2_rn(a2.x, a2.y);
        xl[((unsigned)(n0 + nb + 3) << 6) + pr] = __floats2half2_rn(a3.x, a3.y);
    } else {
        *(float2*)(xr + ((unsigned)(n0 + nb + 0) << 7) + c0) = make_float2(a0.x, a0.y);
        *(float2*)(xr + ((unsigned)(n0 + nb + 1) << 7) + c0) = make_float2(a1.x, a1.y);
        *(float2*)(xr + ((unsigned)(n0 + nb + 2) << 7) + c0) = make_float2(a2.x, a2.y);
        *(float2*)(xr + ((unsigned)(n0 + nb + 3) << 7) + c0) = make_float2(a3.x, a3.y);
    }
}

// ---------------- fused: edge scoring + softmax + aggregate + self-loop -------------
// one wave per dst node; lane owns channels (2*lane, 2*lane+1); head = lane>>4
// (R1-proven structure: VGPR 32, 8 waves/SIMD, 78% VALUBusy)
template<bool OUTHEAD>
__global__ void gat_fused_kernel(const __half2* __restrict__ xl, const float* __restrict__ xr,
                                 const __half2* __restrict__ ea16,
                                 const float* __restrict__ We,
                                 const __half2* __restrict__ weh,
                                 const float* __restrict__ att,
                                 const int* __restrict__ rowstart, const int* __restrict__ csr_src,
                                 const float* __restrict__ bias,
                                 const float* __restrict__ Wout, const float* __restrict__ bout,
                                 float* __restrict__ out) {
    int n = (blockIdx.x * blockDim.x + threadIdx.x) >> 6;
    int lane = threadIdx.x & 63;
    if (n >= NN) return;
    n = __builtin_amdgcn_readfirstlane(n);
    int start = __builtin_amdgcn_readfirstlane(rowstart[n]);
    int end   = __builtin_amdgcn_readfirstlane(rowstart[n + 1]);
    int deg = end - start;
    int c0 = 2 * lane;

    // prefetch self-loop x row early (waited at the very end)
    __half2 xLh = xl[((unsigned)n << 6) + lane];
    v2f xrv = *(const v2f*)(xr + ((unsigned)n << 7) + c0);
    v2f attv = *(const v2f*)(att + c0) * LOG2E;

#if HAVE_FDOT2
    (void)We;
    // half2 weight pairs for lane's two channels: rows c0 and c0+1 are contiguous
    v2h wh0[8], wh1[8];
    {
        const float4* pw = (const float4*)(weh + (size_t)c0 * 8);
        float4 q0 = pw[0], q1 = pw[1], q2 = pw[2], q3 = pw[3];
        float t[16];
        *(float4*)(t)      = q0; *(float4*)(t + 4)  = q1;
        *(float4*)(t + 8)  = q2; *(float4*)(t + 12) = q3;
        #pragma unroll
        for (int k = 0; k < 8; k++) {
            wh0[k] = __builtin_bit_cast(v2h, t[k]);
            wh1[k] = __builtin_bit_cast(v2h, t[8 + k]);
        }
    }
    // project 16 fp16 edge-attr values (as 2 float4 raws): 16 x v_dot2_f32_f16
    auto proj = [&](float4 r0, float4 r1) -> v2f {
        float e[8];
        *(float4*)(e) = r0; *(float4*)(e + 4) = r1;
        float a0 = 0.f, a1 = 0.f;
        #pragma unroll
        for (int k = 0; k < 8; k++) {
            v2h ek = __builtin_bit_cast(v2h, e[k]);
            a0 = __builtin_amdgcn_fdot2(ek, wh0[k], a0, false);
            a1 = __builtin_amdgcn_fdot2(ek, wh1[k], a1, false);
        }
        return (v2f){a0, a1};
    };
#else
    (void)weh;
    v2f wv[16];
    {
        const float* ra = We + c0 * EDD;
        const float* rb = ra + EDD;
        float4 a0 = *(const float4*)(ra),     a1 = *(const float4*)(ra + 4);
        float4 a2 = *(const float4*)(ra + 8), a3 = *(const float4*)(ra + 12);
        float4 b0 = *(const float4*)(rb),     b1 = *(const float4*)(rb + 4);
        float4 b2 = *(const float4*)(rb + 8), b3 = *(const float4*)(rb + 12);
        wv[0]=(v2f){a0.x,b0.x}; wv[1]=(v2f){a0.y,b0.y}; wv[2]=(v2f){a0.z,b0.z}; wv[3]=(v2f){a0.w,b0.w};
        wv[4]=(v2f){a1.x,b1.x}; wv[5]=(v2f){a1.y,b1.y}; wv[6]=(v2f){a1.z,b1.z}; wv[7]=(v2f){a1.w,b1.w};
        wv[8]=(v2f){a2.x,b2.x}; wv[9]=(v2f){a2.y,b2.y}; wv[10]=(v2f){a2.z,b2.z}; wv[11]=(v2f){a2.w,b2.w};
        wv[12]=(v2f){a3.x,b3.x}; wv[13]=(v2f){a3.y,b3.y}; wv[14]=(v2f){a3.z,b3.z}; wv[15]=(v2f){a3.w,b3.w};
    }
    auto proj = [&](float4 r0, float4 r1) -> v2f {
        float2 t0 = unpk(r0.x), t1 = unpk(r0.y), t2 = unpk(r0.z), t3 = unpk(r0.w);
        float2 t4 = unpk(r1.x), t5 = unpk(r1.y), t6 = unpk(r1.z), t7 = unpk(r1.w);
        return wv[0]*t0.x  + wv[1]*t0.y  + wv[2]*t1.x  + wv[3]*t1.y
             + wv[4]*t2.x  + wv[5]*t2.y  + wv[6]*t3.x  + wv[7]*t3.y
             + wv[8]*t4.x  + wv[9]*t4.y  + wv[10]*t5.x + wv[11]*t5.y
             + wv[12]*t6.x + wv[13]*t6.y + wv[14]*t7.x + wv[15]*t7.y;
    };
#endif

    float lh = 0.f;
    v2f acc   = (v2f){0.f, 0.f};
    v2f easum = (v2f){0.f, 0.f};

    auto proc = [&](v2f xv, v2f ea) {
        easum += ea;
        v2f z  = xv + xrv + ea;
        v2f mm = lrelu2(z);
        v2f pp = mm * attv;
        float p = pp.x + pp.y;
        // 16-lane head-group sum via DPP (no LDS pipe): xor1, xor2, ror4, ror8
        DPPADD(p, 0xB1);   // quad_perm [1,0,3,2]
        DPPADD(p, 0x4E);   // quad_perm [2,3,0,1]
        DPPADD(p, 0x124);  // row_ror:4
        DPPADD(p, 0x128);  // row_ror:8
        float w = exp2f(p);
        lh  += w;
        acc += xv * w;
    };

    // GATHER: x gathers (dep on idx) + ea loads (index-derived, no dependency) + project
    #define GATHER(i0, S0, S1, S2, S3, X0, X1, X2, X3, E0, E1, E2, E3) do {           \
        __half2 xh0 = xl[((unsigned)(S0) << 6) + lane];                                \
        __half2 xh1 = xl[((unsigned)(S1) << 6) + lane];                                \
        __half2 xh2 = xl[((unsigned)(S2) << 6) + lane];                                \
        __half2 xh3 = xl[((unsigned)(S3) << 6) + lane];                                \
        const float4* ep = (const float4*)(ea16 + ((size_t)(unsigned)(i0) << 3));      \
        float4 r00 = ep[0], r01 = ep[1], r10 = ep[2], r11 = ep[3];                     \
        float4 r20 = ep[4], r21 = ep[5], r30 = ep[6], r31 = ep[7];                     \
        E0 = proj(r00, r01); E1 = proj(r10, r11);                                      \
        E2 = proj(r20, r21); E3 = proj(r30, r31);                                      \
        float2 xf;                                                                     \
        xf = __half22float2(xh0); X0 = (v2f){xf.x, xf.y};                              \
        xf = __half22float2(xh1); X1 = (v2f){xf.x, xf.y};                              \
        xf = __half22float2(xh2); X2 = (v2f){xf.x, xf.y};                              \
        xf = __half22float2(xh3); X3 = (v2f){xf.x, xf.y};                              \
    } while (0)

    int i = start;
    int nf = deg >> 2;
    if (nf > 0) {
        // idx VGPR prefetch one chunk ahead (clamped, branch-free)
        int v0 = csr_src[i],     v1 = csr_src[i + 1],
            v2 = csr_src[i + 2], v3 = csr_src[i + 3];
        int j4 = (i + 4 > EE - 4) ? (EE - 4) : (i + 4);
        int u0 = csr_src[j4],     u1 = csr_src[j4 + 1],
            u2 = csr_src[j4 + 2], u3 = csr_src[j4 + 3];
        int s0 = __builtin_amdgcn_readfirstlane(v0), s1 = __builtin_amdgcn_readfirstlane(v1);
        int s2 = __builtin_amdgcn_readfirstlane(v2), s3 = __builtin_amdgcn_readfirstlane(v3);
        v2f A0x, A1x, A2x, A3x, A0e, A1e, A2e, A3e;
        GATHER(i, s0, s1, s2, s3, A0x, A1x, A2x, A3x, A0e, A1e, A2e, A3e);
        for (int k = 1; k < nf; k++) {
            int jn = i + 4 * (k + 1);
            jn = (jn > EE - 4) ? (EE - 4) : jn;
            int w0 = csr_src[jn],     w1 = csr_src[jn + 1],
                w2 = csr_src[jn + 2], w3 = csr_src[jn + 3];
            int t0 = __builtin_amdgcn_readfirstlane(u0), t1 = __builtin_amdgcn_readfirstlane(u1);
            int t2 = __builtin_amdgcn_readfirstlane(u2), t3 = __builtin_amdgcn_readfirstlane(u3);
            v2f B0x, B1x, B2x, B3x, B0e, B1e, B2e, B3e;
            GATHER(i + 4 * k, t0, t1, t2, t3, B0x, B1x, B2x, B3x, B0e, B1e, B2e, B3e);
            proc(A0x, A0e); proc(A1x, A1e); proc(A2x, A2e); proc(A3x, A3e);
            A0x = B0x; A1x = B1x; A2x = B2x; A3x = B3x;
            A0e = B0e; A1e = B1e; A2e = B2e; A3e = B3e;
            u0 = w0; u1 = w1; u2 = w2; u3 = w3;
        }
        proc(A0x, A0e); proc(A1x, A1e); proc(A2x, A2e); proc(A3x, A3e);
        i += 4 * nf;
    }
    // tail (<=3): issue all loads, then process
    int rem = end - i;
    if (rem > 0) {
        v2f Tx[3], Te[3];
        int sA = __builtin_amdgcn_readfirstlane(csr_src[i]);
        int sB = (rem > 1) ? __builtin_amdgcn_readfirstlane(csr_src[i + 1]) : sA;
        int sC = (rem > 2) ? __builtin_amdgcn_readfirstlane(csr_src[i + 2]) : sA;
        __half2 xh0 = xl[((unsigned)sA << 6) + lane];
        __half2 xh1 = xl[((unsigned)sB << 6) + lane];
        __half2 xh2 = xl[((unsigned)sC << 6) + lane];
        const float4* ep = (const float4*)(ea16 + ((size_t)(unsigned)i << 3));
        int lim2 = (rem > 1) ? 2 : 0, lim4 = (rem > 2) ? 4 : 0;
        float4 r00 = ep[0], r01 = ep[1];
        float4 r10 = ep[lim2], r11 = ep[lim2 + 1];
        float4 r20 = ep[lim4], r21 = ep[lim4 + 1];
        float2 xf;
        xf = __half22float2(xh0); Tx[0] = (v2f){xf.x, xf.y};
        xf = __half22float2(xh1); Tx[1] = (v2f){xf.x, xf.y};
        xf = __half22float2(xh2); Tx[2] = (v2f){xf.x, xf.y};
        Te[0] = proj(r00, r01); Te[1] = proj(r10, r11); Te[2] = proj(r20, r21);
        proc(Tx[0], Te[0]);
        if (rem > 1) proc(Tx[1], Te[1]);
        if (rem > 2) proc(Tx[2], Te[2]);
    }

    // self-loop: We @ mean(eattr) == mean(We @ eattr); src = n
    {
        float invdeg = 1.0f / (float)(deg > 0 ? deg : 1);
        float2 xf = __half22float2(xLh);
        proc((v2f){xf.x, xf.y}, easum * invdeg);
    }

    float inv = 1.0f / lh;
    float acc0 = acc.x * inv, acc1 = acc.y * inv;
    acc0 += __shfl_xor(acc0, 16); acc0 += __shfl_xor(acc0, 32);
    acc1 += __shfl_xor(acc1, 16); acc1 += __shfl_xor(acc1, 32);

    if (!OUTHEAD) {
        if (lane < 16) {
            float2 o = make_float2(acc0 * 0.25f + bias[2 * lane],
                                   acc1 * 0.25f + bias[2 * lane + 1]);
            *(float2*)(out + ((unsigned)n << 5) + 2 * lane) = o;
        }
    } else {
        __shared__ __align__(16) float sh[4][HIDD];
        int w = threadIdx.x >> 6;
        if (lane < 16) {
            sh[w][2 * lane]     = acc0 * 0.25f + bias[2 * lane];
            sh[w][2 * lane + 1] = acc1 * 0.25f + bias[2 * lane + 1];
        }
        float a = bout[lane];
        const float4* wr4 = (const float4*)(Wout + lane * HIDD);
        const float4* sv4 = (const float4*)(&sh[w][0]);
        #pragma unroll
        for (int k = 0; k < 8; k++) {
            float4 s4 = sv4[k], w4 = wr4[k];
            a += s4.x * w4.x + s4.y * w4.y + s4.z * w4.z + s4.w * w4.w;
        }
        out[((unsigned)n << 6) + lane] = lrelu(a);
    }
    #undef GATHER
}

extern "C" void kernel_launch(void* const* d_in, const int* in_sizes, int n_in,
                              void* d_out, int out_size, void* d_ws, size_t ws_size,
                              hipStream_t stream) {
    const float* x     = (const float*)d_in[0];
    const int*   ei    = (const int*)  d_in[1];
    const float* eattr = (const float*)d_in[2];
    const float* W0    = (const float*)d_in[3];
    const float* b0    = (const float*)d_in[4];
    const float* bn_g  = (const float*)d_in[5];
    const float* bn_b  = (const float*)d_in[6];
    const float* bn_m  = (const float*)d_in[7];
    const float* bn_v  = (const float*)d_in[8];
    const float* Wl[2]   = { (const float*)d_in[9],  (const float*)d_in[16] };
    const float* bl[2]   = { (const float*)d_in[10], (const float*)d_in[17] };
    const float* Wr[2]   = { (const float*)d_in[11], (const float*)d_in[18] };
    const float* br[2]   = { (const float*)d_in[12], (const float*)d_in[19] };
    const float* We[2]   = { (const float*)d_in[13], (const float*)d_in[20] };
    const float* att[2]  = { (const float*)d_in[14], (const float*)d_in[21] };
    const float* bias[2] = { (const float*)d_in[15], (const float*)d_in[22] };
    const float* Wout  = (const float*)d_in[23];
    const float* bout  = (const float*)d_in[24];
    float* out = (float*)d_out;

    const int NB = (NN + 1023) / 1024;
    char* p = (char*)d_ws;
    auto carve = [&](size_t bytes) { char* r = p; p += (bytes + 255) & ~(size_t)255; return r; };
    float*   h1       = (float*)  carve((size_t)NN * HIDD * 4);
    __half2* xl       = (__half2*)carve((size_t)NN * HC * 2);
    float*   xr       = (float*)  carve((size_t)NN * HC * 4);
    int*     cnt      = (int*)    carve((size_t)NN * 4);
    int*     cursor   = (int*)    carve((size_t)NN * 4);
    int*     pre      = (int*)    carve((size_t)NN * 4);
    int*     bsum     = (int*)    carve((size_t)64 * 4);
    int*     rowstart = (int*)    carve((size_t)(NN + 1) * 4);
    int*     csr_src  = (int*)    carve((size_t)EE * 4);
    __half2* ea16     = (__half2*)carve((size_t)EE * EDD * 2);
    float*   w0t      = (float*)  carve((size_t)IND * HIDD * 4);
    float*   b0f      = (float*)  carve((size_t)HIDD * 4);
    float*   wlt0     = (float*)  carve((size_t)HIDD * HC * 4);
    float*   wrt0     = (float*)  carve((size_t)HIDD * HC * 4);
    float*   wlt1     = (float*)  carve((size_t)HIDD * HC * 4);
    float*   wrt1     = (float*)  carve((size_t)HIDD * HC * 4);
    __half2* weh0     = (__half2*)carve((size_t)HC * 8 * 4);
    __half2* weh1     = (__half2*)carve((size_t)HC * 8 * 4);

    hipMemsetAsync(cnt, 0, (size_t)NN * 4, stream);

    fold_kernel<<<1, 256, 0, stream>>>(W0, b0, bn_g, bn_b, bn_m, bn_v,
                                       Wl[0], Wr[0], Wl[1], Wr[1], We[0], We[1],
                                       w0t, b0f, wlt0, wrt0, wlt1, wrt1, weh0, weh1);
    count_embed_kernel<<<EE / 256 + NN / 8, 256, 0, stream>>>(
        ei, cnt, x, w0t, b0f, wlt0, bl[0], wrt0, br[0], xl, xr);
    scan1_kernel<<<NB, 1024, 0, stream>>>(cnt, pre, bsum);
    scan3_kernel<<<NB, 1024, 0, stream>>>(rowstart, cursor, pre, bsum, NB);
    scatter_kernel<<<(EE + 255) / 256, 256, 0, stream>>>(ei, cursor, eattr,
                                                         csr_src, ea16);

    gat_fused_kernel<false><<<(NN * 64) / 256, 256, 0, stream>>>(
        xl, xr, ea16, We[0], weh0, att[0], rowstart, csr_src, bias[0], nullptr, nullptr, h1);

    lin_kernel<<<NN / 8, 256, 0, stream>>>(h1, wlt1, bl[1], wrt1, br[1], xl, xr);
    gat_fused_kernel<true><<<(NN * 64) / 256, 256, 0, stream>>>(
        xl, xr, ea16, We[1], weh1, att[1], rowstart, csr_src, bias[1], Wout, bout, out);
}

// Round 10
// 465.565 us; speedup vs baseline: 1.0357x; 1.0357x over previous
//
#include <hip/hip_runtime.h>
#include <hip/hip_fp16.h>
#include <math.h>

#define NN   50000
#define EE   800000
#define IND  128
#define EDD  16
#define HIDD 32
#define NH   4
#define HC   128     // NH*HIDD
#define OUTD 64
#define NEG  0.1f
#define BN_EPS 1e-5f
#define LOG2E 1.44269504088896340736f

typedef __attribute__((ext_vector_type(2))) float v2f;
typedef __attribute__((ext_vector_type(2))) _Float16 v2h;

#if defined(__has_builtin)
#  if __has_builtin(__builtin_amdgcn_fdot2)
#    define HAVE_FDOT2 1
#  else
#    define HAVE_FDOT2 0
#  endif
#else
#  define HAVE_FDOT2 0
#endif

__device__ __forceinline__ float lrelu(float x) { return fmaxf(x, NEG * x); }
__device__ __forceinline__ v2f lrelu2(v2f v) { return __builtin_elementwise_max(v, v * NEG); }
__device__ __forceinline__ float2 unpk(float f) {
    return __half22float2(__builtin_bit_cast(__half2, f));
}

// DPP rotate-add: sum over the 16-lane head group without LDS-pipe traffic.
#define DPPADD(p, CTRL) do {                                                     \
    int _t = __builtin_amdgcn_update_dpp(0, __builtin_bit_cast(int, (p)),        \
                                         (CTRL), 0xF, 0xF, true);                \
    (p) += __builtin_bit_cast(float, _t);                                        \
} while (0)

// ---------------- weight fold/transpose (tiny, runs before count+embed) ----------
__global__ void fold_kernel(const float* __restrict__ W0, const float* __restrict__ b0,
                            const float* __restrict__ g, const float* __restrict__ bb,
                            const float* __restrict__ bm, const float* __restrict__ bv,
                            const float* __restrict__ Wl0, const float* __restrict__ Wr0,
                            const float* __restrict__ Wl1, const float* __restrict__ Wr1,
                            const float* __restrict__ We0, const float* __restrict__ We1,
                            float* __restrict__ w0t, float* __restrict__ b0f,
                            float* __restrict__ wlt0, float* __restrict__ wrt0,
                            float* __restrict__ wlt1, float* __restrict__ wrt1,
                            __half2* __restrict__ weh0, __half2* __restrict__ weh1) {
    int tid = threadIdx.x;
    for (int idx = tid; idx < IND * HIDD; idx += 256) {
        int k = idx >> 5, c = idx & 31;
        float s = g[c] * (1.0f / sqrtf(bv[c] + BN_EPS));
        w0t[idx] = W0[c * IND + k] * s;
    }
    if (tid < HIDD) {
        float s = g[tid] * (1.0f / sqrtf(bv[tid] + BN_EPS));
        b0f[tid] = (b0[tid] - bm[tid]) * s + bb[tid];
    }
    for (int idx = tid; idx < HIDD * HC; idx += 256) {
        int k = idx >> 7, c = idx & 127;
        wlt0[idx] = Wl0[c * HIDD + k];
        wrt0[idx] = Wr0[c * HIDD + k];
        wlt1[idx] = Wl1[c * HIDD + k];
        wrt1[idx] = Wr1[c * HIDD + k];
    }
    // We -> half2 pairs: weh[c*8 + k] = (We[c][2k], We[c][2k+1])
    for (int idx = tid; idx < HC * 8; idx += 256) {
        int c = idx >> 3, k = idx & 7;
        weh0[idx] = __floats2half2_rn(We0[c * EDD + 2 * k], We0[c * EDD + 2 * k + 1]);
        weh1[idx] = __floats2half2_rn(We1[c * EDD + 2 * k], We1[c * EDD + 2 * k + 1]);
    }
}

// ---------------- merged: degree count+rank (atomic) + embed (VALU) ---------------
// Blocks [0, EE/256): count. Blocks [EE/256, EE/256+NN/8): embed+layer-0 linear.
// cnt is padded to ONE COUNTER PER 64B LINE (cnt[d<<4]) to kill same-line
// atomic RMW serialization (16 counters/line -> 1 counter/line).
__global__ void count_embed_kernel(const int* __restrict__ ei, int* __restrict__ cnt,
                                   int* __restrict__ rank,
                                   const float* __restrict__ x,
                                   const float* __restrict__ w0t, const float* __restrict__ b0f,
                                   const float* __restrict__ wlt, const float* __restrict__ bl,
                                   const float* __restrict__ wrt, const float* __restrict__ br,
                                   __half2* __restrict__ xl, float* __restrict__ xr) {
    if (blockIdx.x < EE / 256) {
        int e = blockIdx.x * 256 + threadIdx.x;
        rank[e] = atomicAdd(&cnt[(unsigned)ei[EE + e] << 4], 1);
        return;
    }
    int tid = threadIdx.x;
    int n0 = (blockIdx.x - EE / 256) * 8;
    __shared__ float sx[8 * IND];
    __shared__ float se[8][HIDD];
    *(float4*)(sx + tid * 4) = *(const float4*)(x + (size_t)n0 * IND + tid * 4);
    __syncthreads();
    {
        int r = tid >> 5, c = tid & 31;
        float acc = b0f[c];
        const float* xrow = sx + r * IND;
        #pragma unroll 8
        for (int k = 0; k < IND; k++) acc += xrow[k] * w0t[k * HIDD + c];
        se[r][c] = lrelu(acc);
    }
    __syncthreads();
    int mat = tid >> 7, grp = (tid >> 6) & 1, pr = tid & 63;
    int c0 = 2 * pr;
    const float* WT = mat ? wrt : wlt;
    const float* b  = mat ? br : bl;
    v2f bv2 = (v2f){b[c0], b[c0 + 1]};
    v2f a0 = bv2, a1 = bv2, a2 = bv2, a3 = bv2;
    int nb = grp * 4;
    #pragma unroll
    for (int k = 0; k < HIDD; k++) {
        v2f wk = *(const v2f*)(WT + k * HC + c0);
        a0 += wk * se[nb + 0][k]; a1 += wk * se[nb + 1][k];
        a2 += wk * se[nb + 2][k]; a3 += wk * se[nb + 3][k];
    }
    if (mat == 0) {
        xl[((unsigned)(n0 + nb + 0) << 6) + pr] = __floats2half2_rn(a0.x, a0.y);
        xl[((unsigned)(n0 + nb + 1) << 6) + pr] = __floats2half2_rn(a1.x, a1.y);
        xl[((unsigned)(n0 + nb + 2) << 6) + pr] = __floats2half2_rn(a2.x, a2.y);
        xl[((unsigned)(n0 + nb + 3) << 6) + pr] = __floats2half2_rn(a3.x, a3.y);
    } else {
        *(float2*)(xr + ((unsigned)(n0 + nb + 0) << 7) + c0) = make_float2(a0.x, a0.y);
        *(float2*)(xr + ((unsigned)(n0 + nb + 1) << 7) + c0) = make_float2(a1.x, a1.y);
        *(float2*)(xr + ((unsigned)(n0 + nb + 2) << 7) + c0) = make_float2(a2.x, a2.y);
        *(float2*)(xr + ((unsigned)(n0 + nb + 3) << 7) + c0) = make_float2(a3.x, a3.y);
    }
}

// parallel exclusive scan of cnt[NN] (stride-16 padded) -> rowstart[NN+1]
__global__ void scan1_kernel(const int* cnt, int* pre, int* bsum) {
    int i = blockIdx.x * 1024 + threadIdx.x;
    int lane = threadIdx.x & 63, wid = threadIdx.x >> 6;
    __shared__ int wsum[16];
    int v = (i < NN) ? cnt[(unsigned)i << 4] : 0;
    int s = v;
    #pragma unroll
    for (int off = 1; off < 64; off <<= 1) {
        int t = __shfl_up(s, off);
        if (lane >= off) s += t;
    }
    if (lane == 63) wsum[wid] = s;
    __syncthreads();
    if (wid == 0) {
        int ws = (lane < 16) ? wsum[lane] : 0;
        #pragma unroll
        for (int off = 1; off < 16; off <<= 1) {
            int t = __shfl_up(ws, off);
            if (lane >= off) ws += t;
        }
        if (lane < 16) wsum[lane] = ws;
    }
    __syncthreads();
    int woff = (wid > 0) ? wsum[wid - 1] : 0;
    if (i < NN) pre[i] = woff + s - v;
    if (threadIdx.x == 1023) bsum[blockIdx.x] = wsum[15];
}

__global__ void scan3_kernel(int* rowstart, const int* pre, const int* bsum, int nb) {
    __shared__ int boff_s;
    if (threadIdx.x < 64) {
        int lane = threadIdx.x;
        int v = (lane < nb) ? bsum[lane] : 0;
        int s = v;
        #pragma unroll
        for (int off = 1; off < 64; off <<= 1) {
            int t = __shfl_up(s, off);
            if (lane >= off) s += t;
        }
        if (lane == (int)blockIdx.x) boff_s = s - v;
    }
    __syncthreads();
    int i = blockIdx.x * 1024 + threadIdx.x;
    if (i < NN) rowstart[i] = pre[i] + boff_s;
    if (i == 0) rowstart[NN] = EE;
}

// atomic-free scatter; also reorders edge_attr into CSR order as fp16
__global__ void scatter_kernel(const int* __restrict__ ei, const int* __restrict__ rowstart,
                               const int* __restrict__ rank, const float* __restrict__ eattr,
                               int* __restrict__ csr_src, __half2* __restrict__ ea16) {
    int e = blockIdx.x * blockDim.x + threadIdx.x;
    if (e >= EE) return;
    int d = ei[EE + e];
    int pos = rowstart[d] + rank[e];
    csr_src[pos] = ei[e];
    const float4* src = (const float4*)(eattr + ((size_t)e << 4));
    float4 q0 = src[0], q1 = src[1], q2 = src[2], q3 = src[3];
    __half2 h[8];
    h[0] = __floats2half2_rn(q0.x, q0.y); h[1] = __floats2half2_rn(q0.z, q0.w);
    h[2] = __floats2half2_rn(q1.x, q1.y); h[3] = __floats2half2_rn(q1.z, q1.w);
    h[4] = __floats2half2_rn(q2.x, q2.y); h[5] = __floats2half2_rn(q2.z, q2.w);
    h[6] = __floats2half2_rn(q3.x, q3.y); h[7] = __floats2half2_rn(q3.z, q3.w);
    float4* dst = (float4*)(ea16 + ((size_t)pos << 3));
    dst[0] = *(float4*)&h[0];
    dst[1] = *(float4*)&h[4];
}

// ---------------- per-layer linear: h1 -> xl (fp16), xr (fp32); 8 nodes/block ------
__global__ void lin_kernel(const float* __restrict__ f,
                           const float* __restrict__ wlt, const float* __restrict__ bl,
                           const float* __restrict__ wrt, const float* __restrict__ br,
                           __half2* __restrict__ xl, float* __restrict__ xr) {
    int tid = threadIdx.x;
    int n0 = blockIdx.x * 8;
    __shared__ float se[8][HIDD];
    se[tid >> 5][tid & 31] = f[((unsigned)(n0 + (tid >> 5)) << 5) + (tid & 31)];
    __syncthreads();
    int mat = tid >> 7, grp = (tid >> 6) & 1, pr = tid & 63;
    int c0 = 2 * pr;
    const float* WT = mat ? wrt : wlt;
    const float* b  = mat ? br : bl;
    v2f bv2 = (v2f){b[c0], b[c0 + 1]};
    v2f a0 = bv2, a1 = bv2, a2 = bv2, a3 = bv2;
    int nb = grp * 4;
    #pragma unroll
    for (int k = 0; k < HIDD; k++) {
        v2f wk = *(const v2f*)(WT + k * HC + c0);
        a0 += wk * se[nb + 0][k]; a1 += wk * se[nb + 1][k];
        a2 += wk * se[nb + 2][k]; a3 += wk * se[nb + 3][k];
    }
    if (mat == 0) {
        xl[((unsigned)(n0 + nb + 0) << 6) + pr] = __floats2half2_rn(a0.x, a0.y);
        xl[((unsigned)(n0 + nb + 1) << 6) + pr] = __floats2half2_rn(a1.x, a1.y);
        xl[((unsigned)(n0 + nb + 2) << 6) + pr] = __floats2half2_rn(a2.x, a2.y);
        xl[((unsigned)(n0 + nb + 3) << 6) + pr] = __floats2half2_rn(a3.x, a3.y);
    } else {
        *(float2*)(xr + ((unsigned)(n0 + nb + 0) << 7) + c0) = make_float2(a0.x, a0.y);
        *(float2*)(xr + ((unsigned)(n0 + nb + 1) << 7) + c0) = make_float2(a1.x, a1.y);
        *(float2*)(xr + ((unsigned)(n0 + nb + 2) << 7) + c0) = make_float2(a2.x, a2.y);
        *(float2*)(xr + ((unsigned)(n0 + nb + 3) << 7) + c0) = make_float2(a3.x, a3.y);
    }
}

// ---------------- fused: edge scoring + softmax + aggregate + self-loop -------------
// one wave per dst node; lane owns channels (2*lane, 2*lane+1); head = lane>>4
// (R1-proven structure: VGPR 32, 8 waves/SIMD, 78% VALUBusy)
template<bool OUTHEAD>
__global__ void gat_fused_kernel(const __half2* __restrict__ xl, const float* __restrict__ xr,
                                 const __half2* __restrict__ ea16,
                                 const float* __restrict__ We,
                                 const __half2* __restrict__ weh,
                                 const float* __restrict__ att,
                                 const int* __restrict__ rowstart, const int* __restrict__ csr_src,
                                 const float* __restrict__ bias,
                                 const float* __restrict__ Wout, const float* __restrict__ bout,
                                 float* __restrict__ out) {
    int n = (blockIdx.x * blockDim.x + threadIdx.x) >> 6;
    int lane = threadIdx.x & 63;
    if (n >= NN) return;
    n = __builtin_amdgcn_readfirstlane(n);
    int start = __builtin_amdgcn_readfirstlane(rowstart[n]);
    int end   = __builtin_amdgcn_readfirstlane(rowstart[n + 1]);
    int deg = end - start;
    int c0 = 2 * lane;

    // prefetch self-loop x row early (waited at the very end)
    __half2 xLh = xl[((unsigned)n << 6) + lane];
    v2f xrv = *(const v2f*)(xr + ((unsigned)n << 7) + c0);
    v2f attv = *(const v2f*)(att + c0) * LOG2E;

#if HAVE_FDOT2
    (void)We;
    // half2 weight pairs for lane's two channels: rows c0 and c0+1 are contiguous
    v2h wh0[8], wh1[8];
    {
        const float4* pw = (const float4*)(weh + (size_t)c0 * 8);
        float4 q0 = pw[0], q1 = pw[1], q2 = pw[2], q3 = pw[3];
        float t[16];
        *(float4*)(t)      = q0; *(float4*)(t + 4)  = q1;
        *(float4*)(t + 8)  = q2; *(float4*)(t + 12) = q3;
        #pragma unroll
        for (int k = 0; k < 8; k++) {
            wh0[k] = __builtin_bit_cast(v2h, t[k]);
            wh1[k] = __builtin_bit_cast(v2h, t[8 + k]);
        }
    }
    // project 16 fp16 edge-attr values (as 2 float4 raws): 16 x v_dot2_f32_f16
    auto proj = [&](float4 r0, float4 r1) -> v2f {
        float e[8];
        *(float4*)(e) = r0; *(float4*)(e + 4) = r1;
        float a0 = 0.f, a1 = 0.f;
        #pragma unroll
        for (int k = 0; k < 8; k++) {
            v2h ek = __builtin_bit_cast(v2h, e[k]);
            a0 = __builtin_amdgcn_fdot2(ek, wh0[k], a0, false);
            a1 = __builtin_amdgcn_fdot2(ek, wh1[k], a1, false);
        }
        return (v2f){a0, a1};
    };
#else
    (void)weh;
    v2f wv[16];
    {
        const float* ra = We + c0 * EDD;
        const float* rb = ra + EDD;
        float4 a0 = *(const float4*)(ra),     a1 = *(const float4*)(ra + 4);
        float4 a2 = *(const float4*)(ra + 8), a3 = *(const float4*)(ra + 12);
        float4 b0 = *(const float4*)(rb),     b1 = *(const float4*)(rb + 4);
        float4 b2 = *(const float4*)(rb + 8), b3 = *(const float4*)(rb + 12);
        wv[0]=(v2f){a0.x,b0.x}; wv[1]=(v2f){a0.y,b0.y}; wv[2]=(v2f){a0.z,b0.z}; wv[3]=(v2f){a0.w,b0.w};
        wv[4]=(v2f){a1.x,b1.x}; wv[5]=(v2f){a1.y,b1.y}; wv[6]=(v2f){a1.z,b1.z}; wv[7]=(v2f){a1.w,b1.w};
        wv[8]=(v2f){a2.x,b2.x}; wv[9]=(v2f){a2.y,b2.y}; wv[10]=(v2f){a2.z,b2.z}; wv[11]=(v2f){a2.w,b2.w};
        wv[12]=(v2f){a3.x,b3.x}; wv[13]=(v2f){a3.y,b3.y}; wv[14]=(v2f){a3.z,b3.z}; wv[15]=(v2f){a3.w,b3.w};
    }
    auto proj = [&](float4 r0, float4 r1) -> v2f {
        float2 t0 = unpk(r0.x), t1 = unpk(r0.y), t2 = unpk(r0.z), t3 = unpk(r0.w);
        float2 t4 = unpk(r1.x), t5 = unpk(r1.y), t6 = unpk(r1.z), t7 = unpk(r1.w);
        return wv[0]*t0.x  + wv[1]*t0.y  + wv[2]*t1.x  + wv[3]*t1.y
             + wv[4]*t2.x  + wv[5]*t2.y  + wv[6]*t3.x  + wv[7]*t3.y
             + wv[8]*t4.x  + wv[9]*t4.y  + wv[10]*t5.x + wv[11]*t5.y
             + wv[12]*t6.x + wv[13]*t6.y + wv[14]*t7.x + wv[15]*t7.y;
    };
#endif

    float lh = 0.f;
    v2f acc   = (v2f){0.f, 0.f};
    v2f easum = (v2f){0.f, 0.f};

    auto proc = [&](v2f xv, v2f ea) {
        easum += ea;
        v2f z  = xv + xrv + ea;
        v2f mm = lrelu2(z);
        v2f pp = mm * attv;
        float p = pp.x + pp.y;
        // 16-lane head-group sum via DPP (no LDS pipe): xor1, xor2, ror4, ror8
        DPPADD(p, 0xB1);   // quad_perm [1,0,3,2]
        DPPADD(p, 0x4E);   // quad_perm [2,3,0,1]
        DPPADD(p, 0x124);  // row_ror:4
        DPPADD(p, 0x128);  // row_ror:8
        float w = exp2f(p);
        lh  += w;
        acc += xv * w;
    };

    // GATHER: x gathers (dep on idx) + ea loads (index-derived, no dependency) + project
    #define GATHER(i0, S0, S1, S2, S3, X0, X1, X2, X3, E0, E1, E2, E3) do {           \
        __half2 xh0 = xl[((unsigned)(S0) << 6) + lane];                                \
        __half2 xh1 = xl[((unsigned)(S1) << 6) + lane];                                \
        __half2 xh2 = xl[((unsigned)(S2) << 6) + lane];                                \
        __half2 xh3 = xl[((unsigned)(S3) << 6) + lane];                                \
        const float4* ep = (const float4*)(ea16 + ((size_t)(unsigned)(i0) << 3));      \
        float4 r00 = ep[0], r01 = ep[1], r10 = ep[2], r11 = ep[3];                     \
        float4 r20 = ep[4], r21 = ep[5], r30 = ep[6], r31 = ep[7];                     \
        E0 = proj(r00, r01); E1 = proj(r10, r11);                                      \
        E2 = proj(r20, r21); E3 = proj(r30, r31);                                      \
        float2 xf;                                                                     \
        xf = __half22float2(xh0); X0 = (v2f){xf.x, xf.y};                              \
        xf = __half22float2(xh1); X1 = (v2f){xf.x, xf.y};                              \
        xf = __half22float2(xh2); X2 = (v2f){xf.x, xf.y};                              \
        xf = __half22float2(xh3); X3 = (v2f){xf.x, xf.y};                              \
    } while (0)

    int i = start;
    int nf = deg >> 2;
    if (nf > 0) {
        // idx VGPR prefetch one chunk ahead (clamped, branch-free)
        int v0 = csr_src[i],     v1 = csr_src[i + 1],
            v2 = csr_src[i + 2], v3 = csr_src[i + 3];
        int j4 = (i + 4 > EE - 4) ? (EE - 4) : (i + 4);
        int u0 = csr_src[j4],     u1 = csr_src[j4 + 1],
            u2 = csr_src[j4 + 2], u3 = csr_src[j4 + 3];
        int s0 = __builtin_amdgcn_readfirstlane(v0), s1 = __builtin_amdgcn_readfirstlane(v1);
        int s2 = __builtin_amdgcn_readfirstlane(v2), s3 = __builtin_amdgcn_readfirstlane(v3);
        v2f A0x, A1x, A2x, A3x, A0e, A1e, A2e, A3e;
        GATHER(i, s0, s1, s2, s3, A0x, A1x, A2x, A3x, A0e, A1e, A2e, A3e);
        for (int k = 1; k < nf; k++) {
            int jn = i + 4 * (k + 1);
            jn = (jn > EE - 4) ? (EE - 4) : jn;
            int w0 = csr_src[jn],     w1 = csr_src[jn + 1],
                w2 = csr_src[jn + 2], w3 = csr_src[jn + 3];
            int t0 = __builtin_amdgcn_readfirstlane(u0), t1 = __builtin_amdgcn_readfirstlane(u1);
            int t2 = __builtin_amdgcn_readfirstlane(u2), t3 = __builtin_amdgcn_readfirstlane(u3);
            v2f B0x, B1x, B2x, B3x, B0e, B1e, B2e, B3e;
            GATHER(i + 4 * k, t0, t1, t2, t3, B0x, B1x, B2x, B3x, B0e, B1e, B2e, B3e);
            proc(A0x, A0e); proc(A1x, A1e); proc(A2x, A2e); proc(A3x, A3e);
            A0x = B0x; A1x = B1x; A2x = B2x; A3x = B3x;
            A0e = B0e; A1e = B1e; A2e = B2e; A3e = B3e;
            u0 = w0; u1 = w1; u2 = w2; u3 = w3;
        }
        proc(A0x, A0e); proc(A1x, A1e); proc(A2x, A2e); proc(A3x, A3e);
        i += 4 * nf;
    }
    // tail (<=3): issue all loads, then process
    int rem = end - i;
    if (rem > 0) {
        v2f Tx[3], Te[3];
        int sA = __builtin_amdgcn_readfirstlane(csr_src[i]);
        int sB = (rem > 1) ? __builtin_amdgcn_readfirstlane(csr_src[i + 1]) : sA;
        int sC = (rem > 2) ? __builtin_amdgcn_readfirstlane(csr_src[i + 2]) : sA;
        __half2 xh0 = xl[((unsigned)sA << 6) + lane];
        __half2 xh1 = xl[((unsigned)sB << 6) + lane];
        __half2 xh2 = xl[((unsigned)sC << 6) + lane];
        const float4* ep = (const float4*)(ea16 + ((size_t)(unsigned)i << 3));
        int lim2 = (rem > 1) ? 2 : 0, lim4 = (rem > 2) ? 4 : 0;
        float4 r00 = ep[0], r01 = ep[1];
        float4 r10 = ep[lim2], r11 = ep[lim2 + 1];
        float4 r20 = ep[lim4], r21 = ep[lim4 + 1];
        float2 xf;
        xf = __half22float2(xh0); Tx[0] = (v2f){xf.x, xf.y};
        xf = __half22float2(xh1); Tx[1] = (v2f){xf.x, xf.y};
        xf = __half22float2(xh2); Tx[2] = (v2f){xf.x, xf.y};
        Te[0] = proj(r00, r01); Te[1] = proj(r10, r11); Te[2] = proj(r20, r21);
        proc(Tx[0], Te[0]);
        if (rem > 1) proc(Tx[1], Te[1]);
        if (rem > 2) proc(Tx[2], Te[2]);
    }

    // self-loop: We @ mean(eattr) == mean(We @ eattr); src = n
    {
        float invdeg = 1.0f / (float)(deg > 0 ? deg : 1);
        float2 xf = __half22float2(xLh);
        proc((v2f){xf.x, xf.y}, easum * invdeg);
    }

    float inv = 1.0f / lh;
    float acc0 = acc.x * inv, acc1 = acc.y * inv;
    acc0 += __shfl_xor(acc0, 16); acc0 += __shfl_xor(acc0, 32);
    acc1 += __shfl_xor(acc1, 16); acc1 += __shfl_xor(acc1, 32);

    if (!OUTHEAD) {
        if (lane < 16) {
            float2 o = make_float2(acc0 * 0.25f + bias[2 * lane],
                                   acc1 * 0.25f + bias[2 * lane + 1]);
            *(float2*)(out + ((unsigned)n << 5) + 2 * lane) = o;
        }
    } else {
        __shared__ __align__(16) float sh[4][HIDD];
        int w = threadIdx.x >> 6;
        if (lane < 16) {
            sh[w][2 * lane]     = acc0 * 0.25f + bias[2 * lane];
            sh[w][2 * lane + 1] = acc1 * 0.25f + bias[2 * lane + 1];
        }
        float a = bout[lane];
        const float4* wr4 = (const float4*)(Wout + lane * HIDD);
        const float4* sv4 = (const float4*)(&sh[w][0]);
        #pragma unroll
        for (int k = 0; k < 8; k++) {
            float4 s4 = sv4[k], w4 = wr4[k];
            a += s4.x * w4.x + s4.y * w4.y + s4.z * w4.z + s4.w * w4.w;
        }
        out[((unsigned)n << 6) + lane] = lrelu(a);
    }
    #undef GATHER
}

extern "C" void kernel_launch(void* const* d_in, const int* in_sizes, int n_in,
                              void* d_out, int out_size, void* d_ws, size_t ws_size,
                              hipStream_t stream) {
    const float* x     = (const float*)d_in[0];
    const int*   ei    = (const int*)  d_in[1];
    const float* eattr = (const float*)d_in[2];
    const float* W0    = (const float*)d_in[3];
    const float* b0    = (const float*)d_in[4];
    const float* bn_g  = (const float*)d_in[5];
    const float* bn_b  = (const float*)d_in[6];
    const float* bn_m  = (const float*)d_in[7];
    const float* bn_v  = (const float*)d_in[8];
    const float* Wl[2]   = { (const float*)d_in[9],  (const float*)d_in[16] };
    const float* bl[2]   = { (const float*)d_in[10], (const float*)d_in[17] };
    const float* Wr[2]   = { (const float*)d_in[11], (const float*)d_in[18] };
    const float* br[2]   = { (const float*)d_in[12], (const float*)d_in[19] };
    const float* We[2]   = { (const float*)d_in[13], (const float*)d_in[20] };
    const float* att[2]  = { (const float*)d_in[14], (const float*)d_in[21] };
    const float* bias[2] = { (const float*)d_in[15], (const float*)d_in[22] };
    const float* Wout  = (const float*)d_in[23];
    const float* bout  = (const float*)d_in[24];
    float* out = (float*)d_out;

    const int NB = (NN + 1023) / 1024;
    char* p = (char*)d_ws;
    auto carve = [&](size_t bytes) { char* r = p; p += (bytes + 255) & ~(size_t)255; return r; };
    float*   h1       = (float*)  carve((size_t)NN * HIDD * 4);
    __half2* xl       = (__half2*)carve((size_t)NN * HC * 2);
    float*   xr       = (float*)  carve((size_t)NN * HC * 4);
    int*     cnt      = (int*)    carve((size_t)NN * 64);      // 1 counter per 64B line
    int*     rank     = (int*)    carve((size_t)EE * 4);
    int*     pre      = (int*)    carve((size_t)NN * 4);
    int*     bsum     = (int*)    carve((size_t)64 * 4);
    int*     rowstart = (int*)    carve((size_t)(NN + 1) * 4);
    int*     csr_src  = (int*)    carve((size_t)EE * 4);
    __half2* ea16     = (__half2*)carve((size_t)EE * EDD * 2);
    float*   w0t      = (float*)  carve((size_t)IND * HIDD * 4);
    float*   b0f      = (float*)  carve((size_t)HIDD * 4);
    float*   wlt0     = (float*)  carve((size_t)HIDD * HC * 4);
    float*   wrt0     = (float*)  carve((size_t)HIDD * HC * 4);
    float*   wlt1     = (float*)  carve((size_t)HIDD * HC * 4);
    float*   wrt1     = (float*)  carve((size_t)HIDD * HC * 4);
    __half2* weh0     = (__half2*)carve((size_t)HC * 8 * 4);
    __half2* weh1     = (__half2*)carve((size_t)HC * 8 * 4);

    hipMemsetAsync(cnt, 0, (size_t)NN * 64, stream);

    fold_kernel<<<1, 256, 0, stream>>>(W0, b0, bn_g, bn_b, bn_m, bn_v,
                                       Wl[0], Wr[0], Wl[1], Wr[1], We[0], We[1],
                                       w0t, b0f, wlt0, wrt0, wlt1, wrt1, weh0, weh1);
    count_embed_kernel<<<EE / 256 + NN / 8, 256, 0, stream>>>(
        ei, cnt, rank, x, w0t, b0f, wlt0, bl[0], wrt0, br[0], xl, xr);
    scan1_kernel<<<NB, 1024, 0, stream>>>(cnt, pre, bsum);
    scan3_kernel<<<NB, 1024, 0, stream>>>(rowstart, pre, bsum, NB);
    scatter_kernel<<<(EE + 255) / 256, 256, 0, stream>>>(ei, rowstart, rank, eattr,
                                                         csr_src, ea16);

    gat_fused_kernel<false><<<(NN * 64) / 256, 256, 0, stream>>>(
        xl, xr, ea16, We[0], weh0, att[0], rowstart, csr_src, bias[0], nullptr, nullptr, h1);

    lin_kernel<<<NN / 8, 256, 0, stream>>>(h1, wlt1, bl[1], wrt1, br[1], xl, xr);
    gat_fused_kernel<true><<<(NN * 64) / 256, 256, 0, stream>>>(
        xl, xr, ea16, We[1], weh1, att[1], rowstart, csr_src, bias[1], Wout, bout, out);
}

// Round 11
// 448.442 us; speedup vs baseline: 1.0752x; 1.0382x over previous
//
#include <hip/hip_runtime.h>
#include <hip/hip_fp16.h>
#include <math.h>

#define NN   50000
#define EE   800000
#define IND  128
#define EDD  16
#define HIDD 32
#define NH   4
#define HC   128     // NH*HIDD
#define OUTD 64
#define NEG  0.1f
#define BN_EPS 1e-5f
#define LOG2E 1.44269504088896340736f

typedef __attribute__((ext_vector_type(2))) float v2f;
typedef __attribute__((ext_vector_type(2))) _Float16 v2h;

#if defined(__has_builtin)
#  if __has_builtin(__builtin_amdgcn_fdot2)
#    define HAVE_FDOT2 1
#  else
#    define HAVE_FDOT2 0
#  endif
#else
#  define HAVE_FDOT2 0
#endif

__device__ __forceinline__ float lrelu(float x) { return fmaxf(x, NEG * x); }
__device__ __forceinline__ v2f lrelu2(v2f v) { return __builtin_elementwise_max(v, v * NEG); }
__device__ __forceinline__ float2 unpk(float f) {
    return __half22float2(__builtin_bit_cast(__half2, f));
}

// DPP rotate-add: sum over the 16-lane head group without LDS-pipe traffic.
#define DPPADD(p, CTRL) do {                                                     \
    int _t = __builtin_amdgcn_update_dpp(0, __builtin_bit_cast(int, (p)),        \
                                         (CTRL), 0xF, 0xF, true);                \
    (p) += __builtin_bit_cast(float, _t);                                        \
} while (0)

// ---------------- weight fold/transpose (tiny, runs before count+embed) ----------
__global__ void fold_kernel(const float* __restrict__ W0, const float* __restrict__ b0,
                            const float* __restrict__ g, const float* __restrict__ bb,
                            const float* __restrict__ bm, const float* __restrict__ bv,
                            const float* __restrict__ Wl0, const float* __restrict__ Wr0,
                            const float* __restrict__ Wl1, const float* __restrict__ Wr1,
                            const float* __restrict__ We0, const float* __restrict__ We1,
                            float* __restrict__ w0t, float* __restrict__ b0f,
                            float* __restrict__ wlt0, float* __restrict__ wrt0,
                            float* __restrict__ wlt1, float* __restrict__ wrt1,
                            __half2* __restrict__ weh0, __half2* __restrict__ weh1) {
    int tid = threadIdx.x;
    for (int idx = tid; idx < IND * HIDD; idx += 256) {
        int k = idx >> 5, c = idx & 31;
        float s = g[c] * (1.0f / sqrtf(bv[c] + BN_EPS));
        w0t[idx] = W0[c * IND + k] * s;
    }
    if (tid < HIDD) {
        float s = g[tid] * (1.0f / sqrtf(bv[tid] + BN_EPS));
        b0f[tid] = (b0[tid] - bm[tid]) * s + bb[tid];
    }
    for (int idx = tid; idx < HIDD * HC; idx += 256) {
        int k = idx >> 7, c = idx & 127;
        wlt0[idx] = Wl0[c * HIDD + k];
        wrt0[idx] = Wr0[c * HIDD + k];
        wlt1[idx] = Wl1[c * HIDD + k];
        wrt1[idx] = Wr1[c * HIDD + k];
    }
    // We -> half2 pairs: weh[c*8 + k] = (We[c][2k], We[c][2k+1])
    for (int idx = tid; idx < HC * 8; idx += 256) {
        int c = idx >> 3, k = idx & 7;
        weh0[idx] = __floats2half2_rn(We0[c * EDD + 2 * k], We0[c * EDD + 2 * k + 1]);
        weh1[idx] = __floats2half2_rn(We1[c * EDD + 2 * k], We1[c * EDD + 2 * k + 1]);
    }
}

// ---------------- merged: count+rank (atomic) + ea16 convert + embed (VALU) -------
// Blocks [0, EE/256): count+rank AND eattr->fp16 conversion in EDGE order
// (coalesced; hides under the atomic round-trip latency these waves pay anyway).
// Blocks [EE/256, ...): embed+layer-0 linear.
// cnt is padded to one counter per 64B line (cnt[d<<4]).
__global__ void count_embed_kernel(const int* __restrict__ ei, int* __restrict__ cnt,
                                   int* __restrict__ rank,
                                   const float* __restrict__ eattr,
                                   __half2* __restrict__ ea16,
                                   const float* __restrict__ x,
                                   const float* __restrict__ w0t, const float* __restrict__ b0f,
                                   const float* __restrict__ wlt, const float* __restrict__ bl,
                                   const float* __restrict__ wrt, const float* __restrict__ br,
                                   __half2* __restrict__ xl, float* __restrict__ xr) {
    if (blockIdx.x < EE / 256) {
        int e = blockIdx.x * 256 + threadIdx.x;
        // issue eattr loads + atomic together; conversion fills the latency shadow
        const float4* src = (const float4*)(eattr + ((size_t)e << 4));
        float4 q0 = src[0], q1 = src[1], q2 = src[2], q3 = src[3];
        rank[e] = atomicAdd(&cnt[(unsigned)ei[EE + e] << 4], 1);
        __half2 h[8];
        h[0] = __floats2half2_rn(q0.x, q0.y); h[1] = __floats2half2_rn(q0.z, q0.w);
        h[2] = __floats2half2_rn(q1.x, q1.y); h[3] = __floats2half2_rn(q1.z, q1.w);
        h[4] = __floats2half2_rn(q2.x, q2.y); h[5] = __floats2half2_rn(q2.z, q2.w);
        h[6] = __floats2half2_rn(q3.x, q3.y); h[7] = __floats2half2_rn(q3.z, q3.w);
        float4* dst = (float4*)(ea16 + ((size_t)e << 3));
        dst[0] = *(float4*)&h[0];
        dst[1] = *(float4*)&h[4];
        return;
    }
    int tid = threadIdx.x;
    int n0 = (blockIdx.x - EE / 256) * 8;
    __shared__ float sx[8 * IND];
    __shared__ float se[8][HIDD];
    *(float4*)(sx + tid * 4) = *(const float4*)(x + (size_t)n0 * IND + tid * 4);
    __syncthreads();
    {
        int r = tid >> 5, c = tid & 31;
        float acc = b0f[c];
        const float* xrow = sx + r * IND;
        #pragma unroll 8
        for (int k = 0; k < IND; k++) acc += xrow[k] * w0t[k * HIDD + c];
        se[r][c] = lrelu(acc);
    }
    __syncthreads();
    int mat = tid >> 7, grp = (tid >> 6) & 1, pr = tid & 63;
    int c0 = 2 * pr;
    const float* WT = mat ? wrt : wlt;
    const float* b  = mat ? br : bl;
    v2f bv2 = (v2f){b[c0], b[c0 + 1]};
    v2f a0 = bv2, a1 = bv2, a2 = bv2, a3 = bv2;
    int nb = grp * 4;
    #pragma unroll
    for (int k = 0; k < HIDD; k++) {
        v2f wk = *(const v2f*)(WT + k * HC + c0);
        a0 += wk * se[nb + 0][k]; a1 += wk * se[nb + 1][k];
        a2 += wk * se[nb + 2][k]; a3 += wk * se[nb + 3][k];
    }
    if (mat == 0) {
        xl[((unsigned)(n0 + nb + 0) << 6) + pr] = __floats2half2_rn(a0.x, a0.y);
        xl[((unsigned)(n0 + nb + 1) << 6) + pr] = __floats2half2_rn(a1.x, a1.y);
        xl[((unsigned)(n0 + nb + 2) << 6) + pr] = __floats2half2_rn(a2.x, a2.y);
        xl[((unsigned)(n0 + nb + 3) << 6) + pr] = __floats2half2_rn(a3.x, a3.y);
    } else {
        *(float2*)(xr + ((unsigned)(n0 + nb + 0) << 7) + c0) = make_float2(a0.x, a0.y);
        *(float2*)(xr + ((unsigned)(n0 + nb + 1) << 7) + c0) = make_float2(a1.x, a1.y);
        *(float2*)(xr + ((unsigned)(n0 + nb + 2) << 7) + c0) = make_float2(a2.x, a2.y);
        *(float2*)(xr + ((unsigned)(n0 + nb + 3) << 7) + c0) = make_float2(a3.x, a3.y);
    }
}

// parallel exclusive scan of cnt[NN] (stride-16 padded) -> rowstart[NN+1]
__global__ void scan1_kernel(const int* cnt, int* pre, int* bsum) {
    int i = blockIdx.x * 1024 + threadIdx.x;
    int lane = threadIdx.x & 63, wid = threadIdx.x >> 6;
    __shared__ int wsum[16];
    int v = (i < NN) ? cnt[(unsigned)i << 4] : 0;
    int s = v;
    #pragma unroll
    for (int off = 1; off < 64; off <<= 1) {
        int t = __shfl_up(s, off);
        if (lane >= off) s += t;
    }
    if (lane == 63) wsum[wid] = s;
    __syncthreads();
    if (wid == 0) {
        int ws = (lane < 16) ? wsum[lane] : 0;
        #pragma unroll
        for (int off = 1; off < 16; off <<= 1) {
            int t = __shfl_up(ws, off);
            if (lane >= off) ws += t;
        }
        if (lane < 16) wsum[lane] = ws;
    }
    __syncthreads();
    int woff = (wid > 0) ? wsum[wid - 1] : 0;
    if (i < NN) pre[i] = woff + s - v;
    if (threadIdx.x == 1023) bsum[blockIdx.x] = wsum[15];
}

__global__ void scan3_kernel(int* rowstart, const int* pre, const int* bsum, int nb) {
    __shared__ int boff_s;
    if (threadIdx.x < 64) {
        int lane = threadIdx.x;
        int v = (lane < nb) ? bsum[lane] : 0;
        int s = v;
        #pragma unroll
        for (int off = 1; off < 64; off <<= 1) {
            int t = __shfl_up(s, off);
            if (lane >= off) s += t;
        }
        if (lane == (int)blockIdx.x) boff_s = s - v;
    }
    __syncthreads();
    int i = blockIdx.x * 1024 + threadIdx.x;
    if (i < NN) rowstart[i] = pre[i] + boff_s;
    if (i == 0) rowstart[NN] = EE;
}

// atomic-free scatter: ONLY writes {src, eid} (8B) per edge to its CSR slot.
// ea16 stays in edge order (converted in count_embed); gat reads it via eid.
__global__ void scatter_kernel(const int* __restrict__ ei, const int* __restrict__ rowstart,
                               const int* __restrict__ rank, int2* __restrict__ csr2) {
    int e = blockIdx.x * blockDim.x + threadIdx.x;
    if (e >= EE) return;
    int d = ei[EE + e];
    int pos = rowstart[d] + rank[e];
    csr2[pos] = make_int2(ei[e], e);
}

// ---------------- per-layer linear: h1 -> xl (fp16), xr (fp32); 8 nodes/block ------
__global__ void lin_kernel(const float* __restrict__ f,
                           const float* __restrict__ wlt, const float* __restrict__ bl,
                           const float* __restrict__ wrt, const float* __restrict__ br,
                           __half2* __restrict__ xl, float* __restrict__ xr) {
    int tid = threadIdx.x;
    int n0 = blockIdx.x * 8;
    __shared__ float se[8][HIDD];
    se[tid >> 5][tid & 31] = f[((unsigned)(n0 + (tid >> 5)) << 5) + (tid & 31)];
    __syncthreads();
    int mat = tid >> 7, grp = (tid >> 6) & 1, pr = tid & 63;
    int c0 = 2 * pr;
    const float* WT = mat ? wrt : wlt;
    const float* b  = mat ? br : bl;
    v2f bv2 = (v2f){b[c0], b[c0 + 1]};
    v2f a0 = bv2, a1 = bv2, a2 = bv2, a3 = bv2;
    int nb = grp * 4;
    #pragma unroll
    for (int k = 0; k < HIDD; k++) {
        v2f wk = *(const v2f*)(WT + k * HC + c0);
        a0 += wk * se[nb + 0][k]; a1 += wk * se[nb + 1][k];
        a2 += wk * se[nb + 2][k]; a3 += wk * se[nb + 3][k];
    }
    if (mat == 0) {
        xl[((unsigned)(n0 + nb + 0) << 6) + pr] = __floats2half2_rn(a0.x, a0.y);
        xl[((unsigned)(n0 + nb + 1) << 6) + pr] = __floats2half2_rn(a1.x, a1.y);
        xl[((unsigned)(n0 + nb + 2) << 6) + pr] = __floats2half2_rn(a2.x, a2.y);
        xl[((unsigned)(n0 + nb + 3) << 6) + pr] = __floats2half2_rn(a3.x, a3.y);
    } else {
        *(float2*)(xr + ((unsigned)(n0 + nb + 0) << 7) + c0) = make_float2(a0.x, a0.y);
        *(float2*)(xr + ((unsigned)(n0 + nb + 1) << 7) + c0) = make_float2(a1.x, a1.y);
        *(float2*)(xr + ((unsigned)(n0 + nb + 2) << 7) + c0) = make_float2(a2.x, a2.y);
        *(float2*)(xr + ((unsigned)(n0 + nb + 3) << 7) + c0) = make_float2(a3.x, a3.y);
    }
}

// ---------------- fused: edge scoring + softmax + aggregate + self-loop -------------
// one wave per dst node; lane owns channels (2*lane, 2*lane+1); head = lane>>4
// csr2: {src,eid} 8B/edge; ea16 in EDGE order, read via eid (broadcast 32B rows,
// prefetched one chunk ahead together with src indices).
template<bool OUTHEAD>
__global__ void gat_fused_kernel(const __half2* __restrict__ xl, const float* __restrict__ xr,
                                 const __half2* __restrict__ ea16,
                                 const float* __restrict__ We,
                                 const __half2* __restrict__ weh,
                                 const float* __restrict__ att,
                                 const int* __restrict__ rowstart, const int2* __restrict__ csr2,
                                 const float* __restrict__ bias,
                                 const float* __restrict__ Wout, const float* __restrict__ bout,
                                 float* __restrict__ out) {
    int n = (blockIdx.x * blockDim.x + threadIdx.x) >> 6;
    int lane = threadIdx.x & 63;
    if (n >= NN) return;
    n = __builtin_amdgcn_readfirstlane(n);
    int start = __builtin_amdgcn_readfirstlane(rowstart[n]);
    int end   = __builtin_amdgcn_readfirstlane(rowstart[n + 1]);
    int deg = end - start;
    int c0 = 2 * lane;

    // prefetch self-loop x row early (waited at the very end)
    __half2 xLh = xl[((unsigned)n << 6) + lane];
    v2f xrv = *(const v2f*)(xr + ((unsigned)n << 7) + c0);
    v2f attv = *(const v2f*)(att + c0) * LOG2E;

#if HAVE_FDOT2
    (void)We;
    // half2 weight pairs for lane's two channels: rows c0 and c0+1 are contiguous
    v2h wh0[8], wh1[8];
    {
        const float4* pw = (const float4*)(weh + (size_t)c0 * 8);
        float4 q0 = pw[0], q1 = pw[1], q2 = pw[2], q3 = pw[3];
        float t[16];
        *(float4*)(t)      = q0; *(float4*)(t + 4)  = q1;
        *(float4*)(t + 8)  = q2; *(float4*)(t + 12) = q3;
        #pragma unroll
        for (int k = 0; k < 8; k++) {
            wh0[k] = __builtin_bit_cast(v2h, t[k]);
            wh1[k] = __builtin_bit_cast(v2h, t[8 + k]);
        }
    }
    // project 16 fp16 edge-attr values (as 2 float4 raws): 16 x v_dot2_f32_f16
    auto proj = [&](float4 r0, float4 r1) -> v2f {
        float e[8];
        *(float4*)(e) = r0; *(float4*)(e + 4) = r1;
        float a0 = 0.f, a1 = 0.f;
        #pragma unroll
        for (int k = 0; k < 8; k++) {
            v2h ek = __builtin_bit_cast(v2h, e[k]);
            a0 = __builtin_amdgcn_fdot2(ek, wh0[k], a0, false);
            a1 = __builtin_amdgcn_fdot2(ek, wh1[k], a1, false);
        }
        return (v2f){a0, a1};
    };
#else
    (void)weh;
    v2f wv[16];
    {
        const float* ra = We + c0 * EDD;
        const float* rb = ra + EDD;
        float4 a0 = *(const float4*)(ra),     a1 = *(const float4*)(ra + 4);
        float4 a2 = *(const float4*)(ra + 8), a3 = *(const float4*)(ra + 12);
        float4 b0 = *(const float4*)(rb),     b1 = *(const float4*)(rb + 4);
        float4 b2 = *(const float4*)(rb + 8), b3 = *(const float4*)(rb + 12);
        wv[0]=(v2f){a0.x,b0.x}; wv[1]=(v2f){a0.y,b0.y}; wv[2]=(v2f){a0.z,b0.z}; wv[3]=(v2f){a0.w,b0.w};
        wv[4]=(v2f){a1.x,b1.x}; wv[5]=(v2f){a1.y,b1.y}; wv[6]=(v2f){a1.z,b1.z}; wv[7]=(v2f){a1.w,b1.w};
        wv[8]=(v2f){a2.x,b2.x}; wv[9]=(v2f){a2.y,b2.y}; wv[10]=(v2f){a2.z,b2.z}; wv[11]=(v2f){a2.w,b2.w};
        wv[12]=(v2f){a3.x,b3.x}; wv[13]=(v2f){a3.y,b3.y}; wv[14]=(v2f){a3.z,b3.z}; wv[15]=(v2f){a3.w,b3.w};
    }
    auto proj = [&](float4 r0, float4 r1) -> v2f {
        float2 t0 = unpk(r0.x), t1 = unpk(r0.y), t2 = unpk(r0.z), t3 = unpk(r0.w);
        float2 t4 = unpk(r1.x), t5 = unpk(r1.y), t6 = unpk(r1.z), t7 = unpk(r1.w);
        return wv[0]*t0.x  + wv[1]*t0.y  + wv[2]*t1.x  + wv[3]*t1.y
             + wv[4]*t2.x  + wv[5]*t2.y  + wv[6]*t3.x  + wv[7]*t3.y
             + wv[8]*t4.x  + wv[9]*t4.y  + wv[10]*t5.x + wv[11]*t5.y
             + wv[12]*t6.x + wv[13]*t6.y + wv[14]*t7.x + wv[15]*t7.y;
    };
#endif

    float lh = 0.f;
    v2f acc   = (v2f){0.f, 0.f};
    v2f easum = (v2f){0.f, 0.f};

    auto proc = [&](v2f xv, v2f ea) {
        easum += ea;
        v2f z  = xv + xrv + ea;
        v2f mm = lrelu2(z);
        v2f pp = mm * attv;
        float p = pp.x + pp.y;
        // 16-lane head-group sum via DPP (no LDS pipe): xor1, xor2, ror4, ror8
        DPPADD(p, 0xB1);   // quad_perm [1,0,3,2]
        DPPADD(p, 0x4E);   // quad_perm [2,3,0,1]
        DPPADD(p, 0x124);  // row_ror:4
        DPPADD(p, 0x128);  // row_ror:8
        float w = exp2f(p);
        lh  += w;
        acc += xv * w;
    };

    // GATHER: xl gathers (via scalar src) + ea reads (via eid, broadcast) + project
    #define GATHER(S0, S1, S2, S3, E0i, E1i, E2i, E3i,                                 \
                   X0, X1, X2, X3, E0, E1, E2, E3) do {                                \
        __half2 xh0 = xl[((unsigned)(S0) << 6) + lane];                                \
        __half2 xh1 = xl[((unsigned)(S1) << 6) + lane];                                \
        __half2 xh2 = xl[((unsigned)(S2) << 6) + lane];                                \
        __half2 xh3 = xl[((unsigned)(S3) << 6) + lane];                                \
        const float4* e0p = (const float4*)(ea16 + ((size_t)(unsigned)(E0i) << 3));    \
        const float4* e1p = (const float4*)(ea16 + ((size_t)(unsigned)(E1i) << 3));    \
        const float4* e2p = (const float4*)(ea16 + ((size_t)(unsigned)(E2i) << 3));    \
        const float4* e3p = (const float4*)(ea16 + ((size_t)(unsigned)(E3i) << 3));    \
        float4 r00 = e0p[0], r01 = e0p[1], r10 = e1p[0], r11 = e1p[1];                 \
        float4 r20 = e2p[0], r21 = e2p[1], r30 = e3p[0], r31 = e3p[1];                 \
        E0 = proj(r00, r01); E1 = proj(r10, r11);                                      \
        E2 = proj(r20, r21); E3 = proj(r30, r31);                                      \
        float2 xf;                                                                     \
        xf = __half22float2(xh0); X0 = (v2f){xf.x, xf.y};                              \
        xf = __half22float2(xh1); X1 = (v2f){xf.x, xf.y};                              \
        xf = __half22float2(xh2); X2 = (v2f){xf.x, xf.y};                              \
        xf = __half22float2(xh3); X3 = (v2f){xf.x, xf.y};                              \
    } while (0)

    int i = start;
    int nf = deg >> 2;
    if (nf > 0) {
        // idx chunk prefetch one ahead (clamped, branch-free); int2 = {src, eid}
        int2 v0 = csr2[i],     v1 = csr2[i + 1],
             v2 = csr2[i + 2], v3 = csr2[i + 3];
        int j4 = (i + 4 > EE - 4) ? (EE - 4) : (i + 4);
        int2 u0 = csr2[j4],     u1 = csr2[j4 + 1],
             u2 = csr2[j4 + 2], u3 = csr2[j4 + 3];
        int s0 = __builtin_amdgcn_readfirstlane(v0.x), s1 = __builtin_amdgcn_readfirstlane(v1.x);
        int s2 = __builtin_amdgcn_readfirstlane(v2.x), s3 = __builtin_amdgcn_readfirstlane(v3.x);
        v2f A0x, A1x, A2x, A3x, A0e, A1e, A2e, A3e;
        GATHER(s0, s1, s2, s3, v0.y, v1.y, v2.y, v3.y,
               A0x, A1x, A2x, A3x, A0e, A1e, A2e, A3e);
        for (int k = 1; k < nf; k++) {
            int jn = i + 4 * (k + 1);
            jn = (jn > EE - 4) ? (EE - 4) : jn;
            int2 w0 = csr2[jn],     w1 = csr2[jn + 1],
                 w2 = csr2[jn + 2], w3 = csr2[jn + 3];
            int t0 = __builtin_amdgcn_readfirstlane(u0.x), t1 = __builtin_amdgcn_readfirstlane(u1.x);
            int t2 = __builtin_amdgcn_readfirstlane(u2.x), t3 = __builtin_amdgcn_readfirstlane(u3.x);
            v2f B0x, B1x, B2x, B3x, B0e, B1e, B2e, B3e;
            GATHER(t0, t1, t2, t3, u0.y, u1.y, u2.y, u3.y,
                   B0x, B1x, B2x, B3x, B0e, B1e, B2e, B3e);
            proc(A0x, A0e); proc(A1x, A1e); proc(A2x, A2e); proc(A3x, A3e);
            A0x = B0x; A1x = B1x; A2x = B2x; A3x = B3x;
            A0e = B0e; A1e = B1e; A2e = B2e; A3e = B3e;
            u0 = w0; u1 = w1; u2 = w2; u3 = w3;
        }
        proc(A0x, A0e); proc(A1x, A1e); proc(A2x, A2e); proc(A3x, A3e);
        i += 4 * nf;
    }
    // tail (<=3): issue all loads, then process
    int rem = end - i;
    if (rem > 0) {
        v2f Tx[3], Te[3];
        int2 cA = csr2[i];
        int2 cB = (rem > 1) ? csr2[i + 1] : cA;
        int2 cC = (rem > 2) ? csr2[i + 2] : cA;
        int sA = __builtin_amdgcn_readfirstlane(cA.x);
        int sB = __builtin_amdgcn_readfirstlane(cB.x);
        int sC = __builtin_amdgcn_readfirstlane(cC.x);
        __half2 xh0 = xl[((unsigned)sA << 6) + lane];
        __half2 xh1 = xl[((unsigned)sB << 6) + lane];
        __half2 xh2 = xl[((unsigned)sC << 6) + lane];
        const float4* eAp = (const float4*)(ea16 + ((size_t)(unsigned)cA.y << 3));
        const float4* eBp = (const float4*)(ea16 + ((size_t)(unsigned)cB.y << 3));
        const float4* eCp = (const float4*)(ea16 + ((size_t)(unsigned)cC.y << 3));
        float4 r00 = eAp[0], r01 = eAp[1];
        float4 r10 = eBp[0], r11 = eBp[1];
        float4 r20 = eCp[0], r21 = eCp[1];
        float2 xf;
        xf = __half22float2(xh0); Tx[0] = (v2f){xf.x, xf.y};
        xf = __half22float2(xh1); Tx[1] = (v2f){xf.x, xf.y};
        xf = __half22float2(xh2); Tx[2] = (v2f){xf.x, xf.y};
        Te[0] = proj(r00, r01); Te[1] = proj(r10, r11); Te[2] = proj(r20, r21);
        proc(Tx[0], Te[0]);
        if (rem > 1) proc(Tx[1], Te[1]);
        if (rem > 2) proc(Tx[2], Te[2]);
    }

    // self-loop: We @ mean(eattr) == mean(We @ eattr); src = n
    {
        float invdeg = 1.0f / (float)(deg > 0 ? deg : 1);
        float2 xf = __half22float2(xLh);
        proc((v2f){xf.x, xf.y}, easum * invdeg);
    }

    float inv = 1.0f / lh;
    float acc0 = acc.x * inv, acc1 = acc.y * inv;
    acc0 += __shfl_xor(acc0, 16); acc0 += __shfl_xor(acc0, 32);
    acc1 += __shfl_xor(acc1, 16); acc1 += __shfl_xor(acc1, 32);

    if (!OUTHEAD) {
        if (lane < 16) {
            float2 o = make_float2(acc0 * 0.25f + bias[2 * lane],
                                   acc1 * 0.25f + bias[2 * lane + 1]);
            *(float2*)(out + ((unsigned)n << 5) + 2 * lane) = o;
        }
    } else {
        __shared__ __align__(16) float sh[4][HIDD];
        int w = threadIdx.x >> 6;
        if (lane < 16) {
            sh[w][2 * lane]     = acc0 * 0.25f + bias[2 * lane];
            sh[w][2 * lane + 1] = acc1 * 0.25f + bias[2 * lane + 1];
        }
        float a = bout[lane];
        const float4* wr4 = (const float4*)(Wout + lane * HIDD);
        const float4* sv4 = (const float4*)(&sh[w][0]);
        #pragma unroll
        for (int k = 0; k < 8; k++) {
            float4 s4 = sv4[k], w4 = wr4[k];
            a += s4.x * w4.x + s4.y * w4.y + s4.z * w4.z + s4.w * w4.w;
        }
        out[((unsigned)n << 6) + lane] = lrelu(a);
    }
    #undef GATHER
}

extern "C" void kernel_launch(void* const* d_in, const int* in_sizes, int n_in,
                              void* d_out, int out_size, void* d_ws, size_t ws_size,
                              hipStream_t stream) {
    const float* x     = (const float*)d_in[0];
    const int*   ei    = (const int*)  d_in[1];
    const float* eattr = (const float*)d_in[2];
    const float* W0    = (const float*)d_in[3];
    const float* b0    = (const float*)d_in[4];
    const float* bn_g  = (const float*)d_in[5];
    const float* bn_b  = (const float*)d_in[6];
    const float* bn_m  = (const float*)d_in[7];
    const float* bn_v  = (const float*)d_in[8];
    const float* Wl[2]   = { (const float*)d_in[9],  (const float*)d_in[16] };
    const float* bl[2]   = { (const float*)d_in[10], (const float*)d_in[17] };
    const float* Wr[2]   = { (const float*)d_in[11], (const float*)d_in[18] };
    const float* br[2]   = { (const float*)d_in[12], (const float*)d_in[19] };
    const float* We[2]   = { (const float*)d_in[13], (const float*)d_in[20] };
    const float* att[2]  = { (const float*)d_in[14], (const float*)d_in[21] };
    const float* bias[2] = { (const float*)d_in[15], (const float*)d_in[22] };
    const float* Wout  = (const float*)d_in[23];
    const float* bout  = (const float*)d_in[24];
    float* out = (float*)d_out;

    const int NB = (NN + 1023) / 1024;
    char* p = (char*)d_ws;
    auto carve = [&](size_t bytes) { char* r = p; p += (bytes + 255) & ~(size_t)255; return r; };
    float*   h1       = (float*)  carve((size_t)NN * HIDD * 4);
    __half2* xl       = (__half2*)carve((size_t)NN * HC * 2);
    float*   xr       = (float*)  carve((size_t)NN * HC * 4);
    int*     cnt      = (int*)    carve((size_t)NN * 64);      // 1 counter per 64B line
    int*     rank     = (int*)    carve((size_t)EE * 4);
    int*     pre      = (int*)    carve((size_t)NN * 4);
    int*     bsum     = (int*)    carve((size_t)64 * 4);
    int*     rowstart = (int*)    carve((size_t)(NN + 1) * 4);
    int2*    csr2     = (int2*)   carve((size_t)EE * 8);
    __half2* ea16     = (__half2*)carve((size_t)EE * EDD * 2);
    float*   w0t      = (float*)  carve((size_t)IND * HIDD * 4);
    float*   b0f      = (float*)  carve((size_t)HIDD * 4);
    float*   wlt0     = (float*)  carve((size_t)HIDD * HC * 4);
    float*   wrt0     = (float*)  carve((size_t)HIDD * HC * 4);
    float*   wlt1     = (float*)  carve((size_t)HIDD * HC * 4);
    float*   wrt1     = (float*)  carve((size_t)HIDD * HC * 4);
    __half2* weh0     = (__half2*)carve((size_t)HC * 8 * 4);
    __half2* weh1     = (__half2*)carve((size_t)HC * 8 * 4);

    hipMemsetAsync(cnt, 0, (size_t)NN * 64, stream);

    fold_kernel<<<1, 256, 0, stream>>>(W0, b0, bn_g, bn_b, bn_m, bn_v,
                                       Wl[0], Wr[0], Wl[1], Wr[1], We[0], We[1],
                                       w0t, b0f, wlt0, wrt0, wlt1, wrt1, weh0, weh1);
    count_embed_kernel<<<EE / 256 + NN / 8, 256, 0, stream>>>(
        ei, cnt, rank, eattr, ea16, x, w0t, b0f, wlt0, bl[0], wrt0, br[0], xl, xr);
    scan1_kernel<<<NB, 1024, 0, stream>>>(cnt, pre, bsum);
    scan3_kernel<<<NB, 1024, 0, stream>>>(rowstart, pre, bsum, NB);
    scatter_kernel<<<(EE + 255) / 256, 256, 0, stream>>>(ei, rowstart, rank, csr2);

    gat_fused_kernel<false><<<(NN * 64) / 256, 256, 0, stream>>>(
        xl, xr, ea16, We[0], weh0, att[0], rowstart, csr2, bias[0], nullptr, nullptr, h1);

    lin_kernel<<<NN / 8, 256, 0, stream>>>(h1, wlt1, bl[1], wrt1, br[1], xl, xr);
    gat_fused_kernel<true><<<(NN * 64) / 256, 256, 0, stream>>>(
        xl, xr, ea16, We[1], weh1, att[1], rowstart, csr2, bias[1], Wout, bout, out);
}

// Round 12
// 446.017 us; speedup vs baseline: 1.0811x; 1.0054x over previous
//
#include <hip/hip_runtime.h>
#include <hip/hip_fp16.h>
#include <math.h>

#define NN   50000
#define EE   800000
#define IND  128
#define EDD  16
#define HIDD 32
#define NH   4
#define HC   128     // NH*HIDD
#define OUTD 64
#define NEG  0.1f
#define BN_EPS 1e-5f
#define LOG2E 1.44269504088896340736f
#define NCB  ((EE + 1023) / 1024)   // count blocks, 4 edges/thread

typedef __attribute__((ext_vector_type(2))) float v2f;
typedef __attribute__((ext_vector_type(2))) _Float16 v2h;

#if defined(__has_builtin)
#  if __has_builtin(__builtin_amdgcn_fdot2)
#    define HAVE_FDOT2 1
#  else
#    define HAVE_FDOT2 0
#  endif
#else
#  define HAVE_FDOT2 0
#endif

__device__ __forceinline__ float lrelu(float x) { return fmaxf(x, NEG * x); }
__device__ __forceinline__ v2f lrelu2(v2f v) { return __builtin_elementwise_max(v, v * NEG); }
__device__ __forceinline__ float2 unpk(float f) {
    return __half22float2(__builtin_bit_cast(__half2, f));
}

// DPP rotate-add: sum over the 16-lane head group without LDS-pipe traffic.
#define DPPADD(p, CTRL) do {                                                     \
    int _t = __builtin_amdgcn_update_dpp(0, __builtin_bit_cast(int, (p)),        \
                                         (CTRL), 0xF, 0xF, true);                \
    (p) += __builtin_bit_cast(float, _t);                                        \
} while (0)

// ---------------- weight fold/transpose + cnt zeroing (replaces memset) ----------
__global__ void fold_kernel(const float* __restrict__ W0, const float* __restrict__ b0,
                            const float* __restrict__ g, const float* __restrict__ bb,
                            const float* __restrict__ bm, const float* __restrict__ bv,
                            const float* __restrict__ Wl0, const float* __restrict__ Wr0,
                            const float* __restrict__ Wl1, const float* __restrict__ Wr1,
                            const float* __restrict__ We0, const float* __restrict__ We1,
                            float* __restrict__ w0t, float* __restrict__ b0f,
                            float* __restrict__ wlt0, float* __restrict__ wrt0,
                            float* __restrict__ wlt1, float* __restrict__ wrt1,
                            __half2* __restrict__ weh0, __half2* __restrict__ weh1,
                            int* __restrict__ cnt) {
    int gid = blockIdx.x * 256 + threadIdx.x;
    for (int i = gid; i < NN * 16; i += 64 * 256) cnt[i] = 0;
    if (blockIdx.x != 0) return;
    int tid = threadIdx.x;
    for (int idx = tid; idx < IND * HIDD; idx += 256) {
        int k = idx >> 5, c = idx & 31;
        float s = g[c] * (1.0f / sqrtf(bv[c] + BN_EPS));
        w0t[idx] = W0[c * IND + k] * s;
    }
    if (tid < HIDD) {
        float s = g[tid] * (1.0f / sqrtf(bv[tid] + BN_EPS));
        b0f[tid] = (b0[tid] - bm[tid]) * s + bb[tid];
    }
    for (int idx = tid; idx < HIDD * HC; idx += 256) {
        int k = idx >> 7, c = idx & 127;
        wlt0[idx] = Wl0[c * HIDD + k];
        wrt0[idx] = Wr0[c * HIDD + k];
        wlt1[idx] = Wl1[c * HIDD + k];
        wrt1[idx] = Wr1[c * HIDD + k];
    }
    // We -> half2 pairs: weh[c*8 + k] = (We[c][2k], We[c][2k+1])
    for (int idx = tid; idx < HC * 8; idx += 256) {
        int c = idx >> 3, k = idx & 7;
        weh0[idx] = __floats2half2_rn(We0[c * EDD + 2 * k], We0[c * EDD + 2 * k + 1]);
        weh1[idx] = __floats2half2_rn(We1[c * EDD + 2 * k], We1[c * EDD + 2 * k + 1]);
    }
}

// ---------------- merged: count+rank (atomic) + ea16 convert + embed (VALU) -------
// Blocks [0, NCB): 4 edges/thread — int4 dst load, 4 pipelined atomics, edge-order
// fp16 conversion filling the atomic-latency shadow, int4 rank store.
// Blocks [NCB, ...): embed+layer-0 linear.
// cnt is padded to one counter per 64B line (cnt[d<<4]).
__global__ void count_embed_kernel(const int* __restrict__ ei, int* __restrict__ cnt,
                                   int* __restrict__ rank,
                                   const float* __restrict__ eattr,
                                   __half2* __restrict__ ea16,
                                   const float* __restrict__ x,
                                   const float* __restrict__ w0t, const float* __restrict__ b0f,
                                   const float* __restrict__ wlt, const float* __restrict__ bl,
                                   const float* __restrict__ wrt, const float* __restrict__ br,
                                   __half2* __restrict__ xl, float* __restrict__ xr) {
    if (blockIdx.x < NCB) {
        int base = (blockIdx.x * 256 + threadIdx.x) * 4;
        if (base >= EE) return;   // EE % 4 == 0: thread is fully valid or fully out
        int4 d4 = *(const int4*)(ei + EE + base);
        int r0 = atomicAdd(&cnt[(unsigned)d4.x << 4], 1);
        int r1 = atomicAdd(&cnt[(unsigned)d4.y << 4], 1);
        int r2 = atomicAdd(&cnt[(unsigned)d4.z << 4], 1);
        int r3 = atomicAdd(&cnt[(unsigned)d4.w << 4], 1);
        // conversion for 4 edges fills the atomic round-trip latency
        #pragma unroll
        for (int j = 0; j < 4; j++) {
            int e = base + j;
            const float4* src = (const float4*)(eattr + ((size_t)e << 4));
            float4 q0 = src[0], q1 = src[1], q2 = src[2], q3 = src[3];
            __half2 h[8];
            h[0] = __floats2half2_rn(q0.x, q0.y); h[1] = __floats2half2_rn(q0.z, q0.w);
            h[2] = __floats2half2_rn(q1.x, q1.y); h[3] = __floats2half2_rn(q1.z, q1.w);
            h[4] = __floats2half2_rn(q2.x, q2.y); h[5] = __floats2half2_rn(q2.z, q2.w);
            h[6] = __floats2half2_rn(q3.x, q3.y); h[7] = __floats2half2_rn(q3.z, q3.w);
            float4* dst = (float4*)(ea16 + ((size_t)e << 3));
            dst[0] = *(float4*)&h[0];
            dst[1] = *(float4*)&h[4];
        }
        *(int4*)(rank + base) = make_int4(r0, r1, r2, r3);
        return;
    }
    int tid = threadIdx.x;
    int n0 = (blockIdx.x - NCB) * 8;
    __shared__ float sx[8 * IND];
    __shared__ float se[8][HIDD];
    *(float4*)(sx + tid * 4) = *(const float4*)(x + (size_t)n0 * IND + tid * 4);
    __syncthreads();
    {
        int r = tid >> 5, c = tid & 31;
        float acc = b0f[c];
        const float* xrow = sx + r * IND;
        #pragma unroll 8
        for (int k = 0; k < IND; k++) acc += xrow[k] * w0t[k * HIDD + c];
        se[r][c] = lrelu(acc);
    }
    __syncthreads();
    int mat = tid >> 7, grp = (tid >> 6) & 1, pr = tid & 63;
    int c0 = 2 * pr;
    const float* WT = mat ? wrt : wlt;
    const float* b  = mat ? br : bl;
    v2f bv2 = (v2f){b[c0], b[c0 + 1]};
    v2f a0 = bv2, a1 = bv2, a2 = bv2, a3 = bv2;
    int nb = grp * 4;
    #pragma unroll
    for (int k = 0; k < HIDD; k++) {
        v2f wk = *(const v2f*)(WT + k * HC + c0);
        a0 += wk * se[nb + 0][k]; a1 += wk * se[nb + 1][k];
        a2 += wk * se[nb + 2][k]; a3 += wk * se[nb + 3][k];
    }
    if (mat == 0) {
        xl[((unsigned)(n0 + nb + 0) << 6) + pr] = __floats2half2_rn(a0.x, a0.y);
        xl[((unsigned)(n0 + nb + 1) << 6) + pr] = __floats2half2_rn(a1.x, a1.y);
        xl[((unsigned)(n0 + nb + 2) << 6) + pr] = __floats2half2_rn(a2.x, a2.y);
        xl[((unsigned)(n0 + nb + 3) << 6) + pr] = __floats2half2_rn(a3.x, a3.y);
    } else {
        *(float2*)(xr + ((unsigned)(n0 + nb + 0) << 7) + c0) = make_float2(a0.x, a0.y);
        *(float2*)(xr + ((unsigned)(n0 + nb + 1) << 7) + c0) = make_float2(a1.x, a1.y);
        *(float2*)(xr + ((unsigned)(n0 + nb + 2) << 7) + c0) = make_float2(a2.x, a2.y);
        *(float2*)(xr + ((unsigned)(n0 + nb + 3) << 7) + c0) = make_float2(a3.x, a3.y);
    }
}

// parallel exclusive scan of cnt[NN] (stride-16 padded) -> rowstart[NN+1]
__global__ void scan1_kernel(const int* cnt, int* pre, int* bsum) {
    int i = blockIdx.x * 1024 + threadIdx.x;
    int lane = threadIdx.x & 63, wid = threadIdx.x >> 6;
    __shared__ int wsum[16];
    int v = (i < NN) ? cnt[(unsigned)i << 4] : 0;
    int s = v;
    #pragma unroll
    for (int off = 1; off < 64; off <<= 1) {
        int t = __shfl_up(s, off);
        if (lane >= off) s += t;
    }
    if (lane == 63) wsum[wid] = s;
    __syncthreads();
    if (wid == 0) {
        int ws = (lane < 16) ? wsum[lane] : 0;
        #pragma unroll
        for (int off = 1; off < 16; off <<= 1) {
            int t = __shfl_up(ws, off);
            if (lane >= off) ws += t;
        }
        if (lane < 16) wsum[lane] = ws;
    }
    __syncthreads();
    int woff = (wid > 0) ? wsum[wid - 1] : 0;
    if (i < NN) pre[i] = woff + s - v;
    if (threadIdx.x == 1023) bsum[blockIdx.x] = wsum[15];
}

__global__ void scan3_kernel(int* rowstart, const int* pre, const int* bsum, int nb) {
    __shared__ int boff_s;
    if (threadIdx.x < 64) {
        int lane = threadIdx.x;
        int v = (lane < nb) ? bsum[lane] : 0;
        int s = v;
        #pragma unroll
        for (int off = 1; off < 64; off <<= 1) {
            int t = __shfl_up(s, off);
            if (lane >= off) s += t;
        }
        if (lane == (int)blockIdx.x) boff_s = s - v;
    }
    __syncthreads();
    int i = blockIdx.x * 1024 + threadIdx.x;
    if (i < NN) rowstart[i] = pre[i] + boff_s;
    if (i == 0) rowstart[NN] = EE;
}

// atomic-free scatter: ONLY writes {src, eid} (8B) per edge to its CSR slot.
// ea16 stays in edge order (converted in count_embed); gat reads it via eid.
__global__ void scatter_kernel(const int* __restrict__ ei, const int* __restrict__ rowstart,
                               const int* __restrict__ rank, int2* __restrict__ csr2) {
    int e = blockIdx.x * blockDim.x + threadIdx.x;
    if (e >= EE) return;
    int d = ei[EE + e];
    int pos = rowstart[d] + rank[e];
    csr2[pos] = make_int2(ei[e], e);
}

// ---------------- per-layer linear: h1 -> xl (fp16), xr (fp32); 8 nodes/block ------
__global__ void lin_kernel(const float* __restrict__ f,
                           const float* __restrict__ wlt, const float* __restrict__ bl,
                           const float* __restrict__ wrt, const float* __restrict__ br,
                           __half2* __restrict__ xl, float* __restrict__ xr) {
    int tid = threadIdx.x;
    int n0 = blockIdx.x * 8;
    __shared__ float se[8][HIDD];
    se[tid >> 5][tid & 31] = f[((unsigned)(n0 + (tid >> 5)) << 5) + (tid & 31)];
    __syncthreads();
    int mat = tid >> 7, grp = (tid >> 6) & 1, pr = tid & 63;
    int c0 = 2 * pr;
    const float* WT = mat ? wrt : wlt;
    const float* b  = mat ? br : bl;
    v2f bv2 = (v2f){b[c0], b[c0 + 1]};
    v2f a0 = bv2, a1 = bv2, a2 = bv2, a3 = bv2;
    int nb = grp * 4;
    #pragma unroll
    for (int k = 0; k < HIDD; k++) {
        v2f wk = *(const v2f*)(WT + k * HC + c0);
        a0 += wk * se[nb + 0][k]; a1 += wk * se[nb + 1][k];
        a2 += wk * se[nb + 2][k]; a3 += wk * se[nb + 3][k];
    }
    if (mat == 0) {
        xl[((unsigned)(n0 + nb + 0) << 6) + pr] = __floats2half2_rn(a0.x, a0.y);
        xl[((unsigned)(n0 + nb + 1) << 6) + pr] = __floats2half2_rn(a1.x, a1.y);
        xl[((unsigned)(n0 + nb + 2) << 6) + pr] = __floats2half2_rn(a2.x, a2.y);
        xl[((unsigned)(n0 + nb + 3) << 6) + pr] = __floats2half2_rn(a3.x, a3.y);
    } else {
        *(float2*)(xr + ((unsigned)(n0 + nb + 0) << 7) + c0) = make_float2(a0.x, a0.y);
        *(float2*)(xr + ((unsigned)(n0 + nb + 1) << 7) + c0) = make_float2(a1.x, a1.y);
        *(float2*)(xr + ((unsigned)(n0 + nb + 2) << 7) + c0) = make_float2(a2.x, a2.y);
        *(float2*)(xr + ((unsigned)(n0 + nb + 3) << 7) + c0) = make_float2(a3.x, a3.y);
    }
}

// ---------------- fused: edge scoring + softmax + aggregate + self-loop -------------
// one wave per dst node; lane owns channels (2*lane, 2*lane+1); head = lane>>4
// csr2: {src,eid} 8B/edge; ea16 in EDGE order, read via eid (broadcast 32B rows,
// prefetched one chunk ahead together with src indices).
template<bool OUTHEAD>
__global__ void gat_fused_kernel(const __half2* __restrict__ xl, const float* __restrict__ xr,
                                 const __half2* __restrict__ ea16,
                                 const float* __restrict__ We,
                                 const __half2* __restrict__ weh,
                                 const float* __restrict__ att,
                                 const int* __restrict__ rowstart, const int2* __restrict__ csr2,
                                 const float* __restrict__ bias,
                                 const float* __restrict__ Wout, const float* __restrict__ bout,
                                 float* __restrict__ out) {
    int n = (blockIdx.x * blockDim.x + threadIdx.x) >> 6;
    int lane = threadIdx.x & 63;
    if (n >= NN) return;
    n = __builtin_amdgcn_readfirstlane(n);
    int start = __builtin_amdgcn_readfirstlane(rowstart[n]);
    int end   = __builtin_amdgcn_readfirstlane(rowstart[n + 1]);
    int deg = end - start;
    int c0 = 2 * lane;

    // prefetch self-loop x row early (waited at the very end)
    __half2 xLh = xl[((unsigned)n << 6) + lane];
    v2f xrv = *(const v2f*)(xr + ((unsigned)n << 7) + c0);
    v2f attv = *(const v2f*)(att + c0) * LOG2E;

#if HAVE_FDOT2
    (void)We;
    // half2 weight pairs for lane's two channels: rows c0 and c0+1 are contiguous
    v2h wh0[8], wh1[8];
    {
        const float4* pw = (const float4*)(weh + (size_t)c0 * 8);
        float4 q0 = pw[0], q1 = pw[1], q2 = pw[2], q3 = pw[3];
        float t[16];
        *(float4*)(t)      = q0; *(float4*)(t + 4)  = q1;
        *(float4*)(t + 8)  = q2; *(float4*)(t + 12) = q3;
        #pragma unroll
        for (int k = 0; k < 8; k++) {
            wh0[k] = __builtin_bit_cast(v2h, t[k]);
            wh1[k] = __builtin_bit_cast(v2h, t[8 + k]);
        }
    }
    // project 16 fp16 edge-attr values (as 2 float4 raws): 16 x v_dot2_f32_f16
    auto proj = [&](float4 r0, float4 r1) -> v2f {
        float e[8];
        *(float4*)(e) = r0; *(float4*)(e + 4) = r1;
        float a0 = 0.f, a1 = 0.f;
        #pragma unroll
        for (int k = 0; k < 8; k++) {
            v2h ek = __builtin_bit_cast(v2h, e[k]);
            a0 = __builtin_amdgcn_fdot2(ek, wh0[k], a0, false);
            a1 = __builtin_amdgcn_fdot2(ek, wh1[k], a1, false);
        }
        return (v2f){a0, a1};
    };
#else
    (void)weh;
    v2f wv[16];
    {
        const float* ra = We + c0 * EDD;
        const float* rb = ra + EDD;
        float4 a0 = *(const float4*)(ra),     a1 = *(const float4*)(ra + 4);
        float4 a2 = *(const float4*)(ra + 8), a3 = *(const float4*)(ra + 12);
        float4 b0 = *(const float4*)(rb),     b1 = *(const float4*)(rb + 4);
        float4 b2 = *(const float4*)(rb + 8), b3 = *(const float4*)(rb + 12);
        wv[0]=(v2f){a0.x,b0.x}; wv[1]=(v2f){a0.y,b0.y}; wv[2]=(v2f){a0.z,b0.z}; wv[3]=(v2f){a0.w,b0.w};
        wv[4]=(v2f){a1.x,b1.x}; wv[5]=(v2f){a1.y,b1.y}; wv[6]=(v2f){a1.z,b1.z}; wv[7]=(v2f){a1.w,b1.w};
        wv[8]=(v2f){a2.x,b2.x}; wv[9]=(v2f){a2.y,b2.y}; wv[10]=(v2f){a2.z,b2.z}; wv[11]=(v2f){a2.w,b2.w};
        wv[12]=(v2f){a3.x,b3.x}; wv[13]=(v2f){a3.y,b3.y}; wv[14]=(v2f){a3.z,b3.z}; wv[15]=(v2f){a3.w,b3.w};
    }
    auto proj = [&](float4 r0, float4 r1) -> v2f {
        float2 t0 = unpk(r0.x), t1 = unpk(r0.y), t2 = unpk(r0.z), t3 = unpk(r0.w);
        float2 t4 = unpk(r1.x), t5 = unpk(r1.y), t6 = unpk(r1.z), t7 = unpk(r1.w);
        return wv[0]*t0.x  + wv[1]*t0.y  + wv[2]*t1.x  + wv[3]*t1.y
             + wv[4]*t2.x  + wv[5]*t2.y  + wv[6]*t3.x  + wv[7]*t3.y
             + wv[8]*t4.x  + wv[9]*t4.y  + wv[10]*t5.x + wv[11]*t5.y
             + wv[12]*t6.x + wv[13]*t6.y + wv[14]*t7.x + wv[15]*t7.y;
    };
#endif

    float lh = 0.f;
    v2f acc   = (v2f){0.f, 0.f};
    v2f easum = (v2f){0.f, 0.f};

    auto proc = [&](v2f xv, v2f ea) {
        easum += ea;
        v2f z  = xv + xrv + ea;
        v2f mm = lrelu2(z);
        v2f pp = mm * attv;
        float p = pp.x + pp.y;
        // 16-lane head-group sum via DPP (no LDS pipe): xor1, xor2, ror4, ror8
        DPPADD(p, 0xB1);   // quad_perm [1,0,3,2]
        DPPADD(p, 0x4E);   // quad_perm [2,3,0,1]
        DPPADD(p, 0x124);  // row_ror:4
        DPPADD(p, 0x128);  // row_ror:8
        float w = exp2f(p);
        lh  += w;
        acc += xv * w;
    };

    // GATHER: xl gathers (via scalar src) + ea reads (via eid, broadcast) + project
    #define GATHER(S0, S1, S2, S3, E0i, E1i, E2i, E3i,                                 \
                   X0, X1, X2, X3, E0, E1, E2, E3) do {                                \
        __half2 xh0 = xl[((unsigned)(S0) << 6) + lane];                                \
        __half2 xh1 = xl[((unsigned)(S1) << 6) + lane];                                \
        __half2 xh2 = xl[((unsigned)(S2) << 6) + lane];                                \
        __half2 xh3 = xl[((unsigned)(S3) << 6) + lane];                                \
        const float4* e0p = (const float4*)(ea16 + ((size_t)(unsigned)(E0i) << 3));    \
        const float4* e1p = (const float4*)(ea16 + ((size_t)(unsigned)(E1i) << 3));    \
        const float4* e2p = (const float4*)(ea16 + ((size_t)(unsigned)(E2i) << 3));    \
        const float4* e3p = (const float4*)(ea16 + ((size_t)(unsigned)(E3i) << 3));    \
        float4 r00 = e0p[0], r01 = e0p[1], r10 = e1p[0], r11 = e1p[1];                 \
        float4 r20 = e2p[0], r21 = e2p[1], r30 = e3p[0], r31 = e3p[1];                 \
        E0 = proj(r00, r01); E1 = proj(r10, r11);                                      \
        E2 = proj(r20, r21); E3 = proj(r30, r31);                                      \
        float2 xf;                                                                     \
        xf = __half22float2(xh0); X0 = (v2f){xf.x, xf.y};                              \
        xf = __half22float2(xh1); X1 = (v2f){xf.x, xf.y};                              \
        xf = __half22float2(xh2); X2 = (v2f){xf.x, xf.y};                              \
        xf = __half22float2(xh3); X3 = (v2f){xf.x, xf.y};                              \
    } while (0)

    int i = start;
    int nf = deg >> 2;
    if (nf > 0) {
        // idx chunk prefetch one ahead (clamped, branch-free); int2 = {src, eid}
        int2 v0 = csr2[i],     v1 = csr2[i + 1],
             v2 = csr2[i + 2], v3 = csr2[i + 3];
        int j4 = (i + 4 > EE - 4) ? (EE - 4) : (i + 4);
        int2 u0 = csr2[j4],     u1 = csr2[j4 + 1],
             u2 = csr2[j4 + 2], u3 = csr2[j4 + 3];
        int s0 = __builtin_amdgcn_readfirstlane(v0.x), s1 = __builtin_amdgcn_readfirstlane(v1.x);
        int s2 = __builtin_amdgcn_readfirstlane(v2.x), s3 = __builtin_amdgcn_readfirstlane(v3.x);
        v2f A0x, A1x, A2x, A3x, A0e, A1e, A2e, A3e;
        GATHER(s0, s1, s2, s3, v0.y, v1.y, v2.y, v3.y,
               A0x, A1x, A2x, A3x, A0e, A1e, A2e, A3e);
        for (int k = 1; k < nf; k++) {
            int jn = i + 4 * (k + 1);
            jn = (jn > EE - 4) ? (EE - 4) : jn;
            int2 w0 = csr2[jn],     w1 = csr2[jn + 1],
                 w2 = csr2[jn + 2], w3 = csr2[jn + 3];
            int t0 = __builtin_amdgcn_readfirstlane(u0.x), t1 = __builtin_amdgcn_readfirstlane(u1.x);
            int t2 = __builtin_amdgcn_readfirstlane(u2.x), t3 = __builtin_amdgcn_readfirstlane(u3.x);
            v2f B0x, B1x, B2x, B3x, B0e, B1e, B2e, B3e;
            GATHER(t0, t1, t2, t3, u0.y, u1.y, u2.y, u3.y,
                   B0x, B1x, B2x, B3x, B0e, B1e, B2e, B3e);
            proc(A0x, A0e); proc(A1x, A1e); proc(A2x, A2e); proc(A3x, A3e);
            A0x = B0x; A1x = B1x; A2x = B2x; A3x = B3x;
            A0e = B0e; A1e = B1e; A2e = B2e; A3e = B3e;
            u0 = w0; u1 = w1; u2 = w2; u3 = w3;
        }
        proc(A0x, A0e); proc(A1x, A1e); proc(A2x, A2e); proc(A3x, A3e);
        i += 4 * nf;
    }
    // tail (<=3): issue all loads, then process
    int rem = end - i;
    if (rem > 0) {
        v2f Tx[3], Te[3];
        int2 cA = csr2[i];
        int2 cB = (rem > 1) ? csr2[i + 1] : cA;
        int2 cC = (rem > 2) ? csr2[i + 2] : cA;
        int sA = __builtin_amdgcn_readfirstlane(cA.x);
        int sB = __builtin_amdgcn_readfirstlane(cB.x);
        int sC = __builtin_amdgcn_readfirstlane(cC.x);
        __half2 xh0 = xl[((unsigned)sA << 6) + lane];
        __half2 xh1 = xl[((unsigned)sB << 6) + lane];
        __half2 xh2 = xl[((unsigned)sC << 6) + lane];
        const float4* eAp = (const float4*)(ea16 + ((size_t)(unsigned)cA.y << 3));
        const float4* eBp = (const float4*)(ea16 + ((size_t)(unsigned)cB.y << 3));
        const float4* eCp = (const float4*)(ea16 + ((size_t)(unsigned)cC.y << 3));
        float4 r00 = eAp[0], r01 = eAp[1];
        float4 r10 = eBp[0], r11 = eBp[1];
        float4 r20 = eCp[0], r21 = eCp[1];
        float2 xf;
        xf = __half22float2(xh0); Tx[0] = (v2f){xf.x, xf.y};
        xf = __half22float2(xh1); Tx[1] = (v2f){xf.x, xf.y};
        xf = __half22float2(xh2); Tx[2] = (v2f){xf.x, xf.y};
        Te[0] = proj(r00, r01); Te[1] = proj(r10, r11); Te[2] = proj(r20, r21);
        proc(Tx[0], Te[0]);
        if (rem > 1) proc(Tx[1], Te[1]);
        if (rem > 2) proc(Tx[2], Te[2]);
    }

    // self-loop: We @ mean(eattr) == mean(We @ eattr); src = n
    {
        float invdeg = 1.0f / (float)(deg > 0 ? deg : 1);
        float2 xf = __half22float2(xLh);
        proc((v2f){xf.x, xf.y}, easum * invdeg);
    }

    float inv = 1.0f / lh;
    float acc0 = acc.x * inv, acc1 = acc.y * inv;
    acc0 += __shfl_xor(acc0, 16); acc0 += __shfl_xor(acc0, 32);
    acc1 += __shfl_xor(acc1, 16); acc1 += __shfl_xor(acc1, 32);

    if (!OUTHEAD) {
        if (lane < 16) {
            float2 o = make_float2(acc0 * 0.25f + bias[2 * lane],
                                   acc1 * 0.25f + bias[2 * lane + 1]);
            *(float2*)(out + ((unsigned)n << 5) + 2 * lane) = o;
        }
    } else {
        __shared__ __align__(16) float sh[4][HIDD];
        int w = threadIdx.x >> 6;
        if (lane < 16) {
            sh[w][2 * lane]     = acc0 * 0.25f + bias[2 * lane];
            sh[w][2 * lane + 1] = acc1 * 0.25f + bias[2 * lane + 1];
        }
        float a = bout[lane];
        const float4* wr4 = (const float4*)(Wout + lane * HIDD);
        const float4* sv4 = (const float4*)(&sh[w][0]);
        #pragma unroll
        for (int k = 0; k < 8; k++) {
            float4 s4 = sv4[k], w4 = wr4[k];
            a += s4.x * w4.x + s4.y * w4.y + s4.z * w4.z + s4.w * w4.w;
        }
        out[((unsigned)n << 6) + lane] = lrelu(a);
    }
    #undef GATHER
}

extern "C" void kernel_launch(void* const* d_in, const int* in_sizes, int n_in,
                              void* d_out, int out_size, void* d_ws, size_t ws_size,
                              hipStream_t stream) {
    const float* x     = (const float*)d_in[0];
    const int*   ei    = (const int*)  d_in[1];
    const float* eattr = (const float*)d_in[2];
    const float* W0    = (const float*)d_in[3];
    const float* b0    = (const float*)d_in[4];
    const float* bn_g  = (const float*)d_in[5];
    const float* bn_b  = (const float*)d_in[6];
    const float* bn_m  = (const float*)d_in[7];
    const float* bn_v  = (const float*)d_in[8];
    const float* Wl[2]   = { (const float*)d_in[9],  (const float*)d_in[16] };
    const float* bl[2]   = { (const float*)d_in[10], (const float*)d_in[17] };
    const float* Wr[2]   = { (const float*)d_in[11], (const float*)d_in[18] };
    const float* br[2]   = { (const float*)d_in[12], (const float*)d_in[19] };
    const float* We[2]   = { (const float*)d_in[13], (const float*)d_in[20] };
    const float* att[2]  = { (const float*)d_in[14], (const float*)d_in[21] };
    const float* bias[2] = { (const float*)d_in[15], (const float*)d_in[22] };
    const float* Wout  = (const float*)d_in[23];
    const float* bout  = (const float*)d_in[24];
    float* out = (float*)d_out;

    const int NB = (NN + 1023) / 1024;
    char* p = (char*)d_ws;
    auto carve = [&](size_t bytes) { char* r = p; p += (bytes + 255) & ~(size_t)255; return r; };
    float*   h1       = (float*)  carve((size_t)NN * HIDD * 4);
    __half2* xl       = (__half2*)carve((size_t)NN * HC * 2);
    float*   xr       = (float*)  carve((size_t)NN * HC * 4);
    int*     cnt      = (int*)    carve((size_t)NN * 64);      // 1 counter per 64B line
    int*     rank     = (int*)    carve((size_t)EE * 4);
    int*     pre      = (int*)    carve((size_t)NN * 4);
    int*     bsum     = (int*)    carve((size_t)64 * 4);
    int*     rowstart = (int*)    carve((size_t)(NN + 1) * 4);
    int2*    csr2     = (int2*)   carve((size_t)EE * 8);
    __half2* ea16     = (__half2*)carve((size_t)EE * EDD * 2);
    float*   w0t      = (float*)  carve((size_t)IND * HIDD * 4);
    float*   b0f      = (float*)  carve((size_t)HIDD * 4);
    float*   wlt0     = (float*)  carve((size_t)HIDD * HC * 4);
    float*   wrt0     = (float*)  carve((size_t)HIDD * HC * 4);
    float*   wlt1     = (float*)  carve((size_t)HIDD * HC * 4);
    float*   wrt1     = (float*)  carve((size_t)HIDD * HC * 4);
    __half2* weh0     = (__half2*)carve((size_t)HC * 8 * 4);
    __half2* weh1     = (__half2*)carve((size_t)HC * 8 * 4);

    fold_kernel<<<64, 256, 0, stream>>>(W0, b0, bn_g, bn_b, bn_m, bn_v,
                                        Wl[0], Wr[0], Wl[1], Wr[1], We[0], We[1],
                                        w0t, b0f, wlt0, wrt0, wlt1, wrt1, weh0, weh1,
                                        cnt);
    count_embed_kernel<<<NCB + NN / 8, 256, 0, stream>>>(
        ei, cnt, rank, eattr, ea16, x, w0t, b0f, wlt0, bl[0], wrt0, br[0], xl, xr);
    scan1_kernel<<<NB, 1024, 0, stream>>>(cnt, pre, bsum);
    scan3_kernel<<<NB, 1024, 0, stream>>>(rowstart, pre, bsum, NB);
    scatter_kernel<<<(EE + 255) / 256, 256, 0, stream>>>(ei, rowstart, rank, csr2);

    gat_fused_kernel<false><<<(NN * 64) / 256, 256, 0, stream>>>(
        xl, xr, ea16, We[0], weh0, att[0], rowstart, csr2, bias[0], nullptr, nullptr, h1);

    lin_kernel<<<NN / 8, 256, 0, stream>>>(h1, wlt1, bl[1], wrt1, br[1], xl, xr);
    gat_fused_kernel<true><<<(NN * 64) / 256, 256, 0, stream>>>(
        xl, xr, ea16, We[1], weh1, att[1], rowstart, csr2, bias[1], Wout, bout, out);
}